// Round 12
// baseline (64.292 us; speedup 1.0000x reference)
//
#include <hip/hip_runtime.h>
#include <hip/hip_bf16.h>
#include <math.h>

#define BATCH 256
#define SEQL  4096
#define DIMC  256
#define NPAT  160
#define CNT   (BATCH * SEQL)     // per-stream element count (over B,L)
#define EPS   1e-3f

typedef unsigned int uint;
typedef unsigned short ushort_t;

// ---------------- shared helpers ----------------------------------------------
__device__ __forceinline__ int pad_mask(int type) {
    return (type == 0) ? 0 : (type == 1) ? 3 : (type == 2) ? 1 : (type == 3) ? 16 : 24;
}

// tap value for extended-pattern q, index k in [0,6): k==5 is the constant 1.
__device__ __forceinline__ float tap6(int q, int k) {
    if (k == 5) return 1.0f;
    const int type = q >> 5, bits = q & 31;
    const int pm = pad_mask(type);
    if ((pm >> k) & 1) return 0.0f;
    return ((bits >> k) & 1) ? 1.0f : -1.0f;
}

__device__ __forceinline__ float fast_elu(float x) {
    return x > 0.0f ? x : (__expf(x) - 1.0f);
}

__device__ __forceinline__ int pat_type(int t) {
    if (t >= 2 && t < SEQL - 2) return 0;
    if (t == 0) return 1;
    if (t == 1) return 2;
    if (t == SEQL - 2) return 3;
    return 4;
}

struct PtrPack { const float* p[18]; };  // per stream: Wc, bc, g, be, Wf, bf

// =============================================================================
// k_prep: bit-pack rows (ballot), per-position codes, per-block partial hist
// (non-atomic, no zeroing needed). 256 blocks x 512 threads.  [proven round 3]
// =============================================================================
__global__ __launch_bounds__(512) void k_prep(const float* __restrict__ x,
                                              const int* __restrict__ perms,
                                              uint* __restrict__ part,
                                              ushort_t* __restrict__ codes) {
    __shared__ uint xw[130];    // bit-packed row, 1-word zero sentinel each end
    __shared__ uint xwI[130];
    __shared__ uint h[2 * NPAT];
    const int b = blockIdx.x, tid = threadIdx.x;
    const int lane = tid & 63;

    for (int i = tid; i < 2 * NPAT; i += 512) h[i] = 0;
    if (tid < 2) { xw[tid * 129] = 0; xwI[tid * 129] = 0; }

    const float* xr = x + (size_t)b * SEQL;
    const int* pr = perms + (size_t)b * SEQL;

#pragma unroll
    for (int it = 0; it < 8; ++it) {
        const int i = it * 512 + tid;
        const unsigned long long m = __ballot(xr[i] > 0.5f);
        if (lane == 0) {
            const int w = 1 + ((it * 512 + (tid & ~63)) >> 5);
            xw[w] = (uint)m;
            xw[w + 1] = (uint)(m >> 32);
        }
    }
    __syncthreads();
#pragma unroll
    for (int it = 0; it < 8; ++it) {
        const int i = it * 512 + tid;
        const int p = pr[i];
        const unsigned long long m = __ballot(((xw[1 + (p >> 5)] >> (p & 31)) & 1u) != 0u);
        if (lane == 0) {
            const int w = 1 + ((it * 512 + (tid & ~63)) >> 5);
            xwI[w] = (uint)m;
            xwI[w + 1] = (uint)(m >> 32);
        }
    }
    __syncthreads();

    const int t0 = tid * 8;
    const int w = (t0 + 30) >> 5;
    const int sh0 = (t0 + 30) & 31;
    const unsigned long long Wd = (unsigned long long)xw[w] | ((unsigned long long)xw[w + 1] << 32);
    const unsigned long long Wi = (unsigned long long)xwI[w] | ((unsigned long long)xwI[w + 1] << 32);
    int c[8];
#pragma unroll
    for (int r = 0; r < 8; ++r) {
        const int t = t0 + r;
        const int type = pat_type(t);
        const int qd = type * 32 + (int)((Wd >> (sh0 + r)) & 31ull);
        const int qp = type * 32 + (int)((Wi >> (sh0 + r)) & 31ull);
        atomicAdd(&h[qd], 1u);
        atomicAdd(&h[NPAT + qp], 1u);
        c[r] = qd | (qp << 8);
    }
    uint4 cv;
    cv.x = (uint)(c[0] | (c[1] << 16));
    cv.y = (uint)(c[2] | (c[3] << 16));
    cv.z = (uint)(c[4] | (c[5] << 16));
    cv.w = (uint)(c[6] | (c[7] << 16));
    *(uint4*)(codes + (size_t)b * SEQL + t0) = cv;
    __syncthreads();

    if (tid < 2 * NPAT) part[(size_t)tid * 256 + b] = h[tid];
}

// =============================================================================
// k_mega: 256 blocks x 512 threads. Every block redundantly computes the FULL
// table pipeline (bit-identical across blocks; all static indexing, no scratch,
// pattern-per-thread dots), keeps the 960-float table in LDS, streams its row.
// =============================================================================
__global__ __launch_bounds__(512) void k_mega(PtrPack pk,
                                              const float* __restrict__ Wm,
                                              const float* __restrict__ gm,
                                              const float* __restrict__ bem,
                                              const float* __restrict__ Wo,
                                              const float* __restrict__ bo,
                                              const float* __restrict__ go,
                                              const float* __restrict__ beo,
                                              const uint* __restrict__ part,
                                              const ushort_t* __restrict__ codes,
                                              float* __restrict__ out) {
    const int tid = threadIdx.x;
    const int lane = tid & 63, w = tid >> 6;   // 8 waves

    __shared__ float sh_hist[2 * NPAT];
    __shared__ float m6p[3][21][8];
    __shared__ float sM6[3][21];
    __shared__ float sa[3][5][DIMC];
    __shared__ float sb3[3][DIMC];
    __shared__ float swf3[3][DIMC];
    __shared__ float se[480], snn[480], spre0[480], spre1[480];
    __shared__ float sA[DIMC], sB[DIMC], sWo0[DIMC], sWo1[DIMC];
    __shared__ float2 tb[480];
    __shared__ double wpart[8][4];
    __shared__ double dstat[6];

    // ---- A: reduce partials -> histogram (bin-per-thread, L3-hot 320 KB) ----
    if (tid < 2 * NPAT) {
        const uint4* pp = (const uint4*)(part + (size_t)tid * 256);
        uint s = 0;
#pragma unroll 8
        for (int i = 0; i < 64; ++i) {
            const uint4 v = pp[i];
            s += v.x + v.y + v.z + v.w;
        }
        sh_hist[tid] = (float)s;   // exact: counts < 2^24
    }
    __syncthreads();

    // ---- B: M6 second-moment matrices (3 streams x 21 entries x 8 chunks) ---
    if (tid < 504) {
        const int jj = tid / 168, r = tid % 168;
        const int e = r >> 3, prt = r & 7;
        int k = 0, rem = e;
        while (rem > 5 - k) { rem -= 6 - k; ++k; }
        const int l = k + rem;
        const float* hj = sh_hist + ((jj == 2) ? NPAT : 0);
        float S = 0.0f;
        for (int q = prt * 20; q < prt * 20 + 20; ++q)
            S += hj[q] * tap6(q, k) * tap6(q, l);
        m6p[jj][e][prt] = S;
    }
    __syncthreads();
    if (tid < 63) {
        const int jj = tid / 21, e = tid % 21;
        float S = 0.0f;
#pragma unroll
        for (int p = 0; p < 8; ++p) S += m6p[jj][e][p];
        sM6[jj][e] = S;
    }
    __syncthreads();

    // ---- C: per-channel BN coefficients, all 3 streams (768 units) ----------
    for (int u = tid; u < 768; u += 512) {
        const int j = u >> 8, c = u & 255;
        const float* Wc = pk.p[6 * j + 0];
        const float* bc = pk.p[6 * j + 1];
        const float* g  = pk.p[6 * j + 2];
        const float* be = pk.p[6 * j + 3];
        const float* Wf = pk.p[6 * j + 4];
        float w6[6];
#pragma unroll
        for (int k = 0; k < 5; ++k) w6[k] = Wc[k * DIMC + c];
        w6[5] = bc[c];
        double Ey = 0.0, Ey2 = 0.0;
        {
            int e = 0;
#pragma unroll
            for (int k = 0; k < 6; ++k) {
#pragma unroll
                for (int l = k; l < 6; ++l, ++e) {
                    const double p = (double)w6[k] * (double)w6[l] * (double)sM6[j][e];
                    Ey2 += (l == k) ? p : 2.0 * p;
                    if (l == 5) Ey += (double)w6[k] * (double)sM6[j][e];
                }
            }
        }
        const double mean = Ey / (double)CNT;
        const double var = Ey2 / (double)CNT - mean * mean;
        const float scale = g[c] * rsqrtf((float)var + EPS);
#pragma unroll
        for (int k = 0; k < 5; ++k) sa[j][k][c] = scale * w6[k];
        sb3[j][c] = scale * (w6[5] - (float)mean) + be[c];
        swf3[j][c] = Wf[c];
    }
    if (tid < 480) {
        snn[tid] = sh_hist[(tid >= 2 * NPAT) ? (tid - NPAT) : (tid % NPAT)];
    }
    __syncthreads();

    // ---- D: e-table, ONE PATTERN PER THREAD (no shuffles, LDS broadcast) ----
    if (tid < 480) {
        const int j = tid / 160, q = tid % 160;
        const float tk0 = tap6(q, 0), tk1 = tap6(q, 1), tk2 = tap6(q, 2);
        const float tk3 = tap6(q, 3), tk4 = tap6(q, 4);
        float acc = 0.0f;
#pragma unroll 4
        for (int c = 0; c < DIMC; ++c) {
            float bn = sb3[j][c];
            bn += tk0 * sa[j][0][c];
            bn += tk1 * sa[j][1][c];
            bn += tk2 * sa[j][2][c];
            bn += tk3 * sa[j][3][c];
            bn += tk4 * sa[j][4][c];
            acc += fast_elu(bn) * swf3[j][c];
        }
        se[tid] = acc + pk.p[6 * j + 5][0];
    }
    __syncthreads();

    // ---- E: yt mean/var (weighted f64 over 480 bins) ------------------------
    {
        double d1 = 0.0, d2 = 0.0;
        if (tid < 480) {
            const double n = (double)snn[tid], e = (double)se[tid];
            d1 = n * e; d2 = n * e * e;
        }
#pragma unroll
        for (int off = 32; off; off >>= 1) {
            d1 += __shfl_xor(d1, off);
            d2 += __shfl_xor(d2, off);
        }
        if (lane == 0) { wpart[w][0] = d1; wpart[w][1] = d2; }
        __syncthreads();
        if (tid == 0) {
            double a = 0.0, b2 = 0.0;
#pragma unroll
            for (int i = 0; i < 8; ++i) { a += wpart[i][0]; b2 += wpart[i][1]; }
            dstat[0] = a; dstat[1] = b2;
        }
        __syncthreads();
    }
    const double mean_yt = dstat[0] / (3.0 * (double)CNT);
    const double var_yt  = dstat[1] / (3.0 * (double)CNT) - mean_yt * mean_yt;

    // ---- F: middle-unit affine coefficients ---------------------------------
    if (tid < DIMC) {
        const float wm = Wm[tid];
        sA[tid] = gm[tid] * wm * rsqrtf(wm * wm * (float)var_yt + EPS);
        sB[tid] = bem[tid];
        sWo0[tid] = Wo[tid * 2 + 0];
        sWo1[tid] = Wo[tid * 2 + 1];
    }
    __syncthreads();

    // ---- G: pre-activations, ONE PATTERN PER THREAD -------------------------
    if (tid < 480) {
        const float du = se[tid] - (float)mean_yt;
        float a0 = bo[0], a1 = bo[1];
#pragma unroll 4
        for (int c = 0; c < DIMC; ++c) {
            const float mo = fast_elu(sA[c] * du + sB[c]);
            a0 += mo * sWo0[c];
            a1 += mo * sWo1[c];
        }
        spre0[tid] = a0;
        spre1[tid] = a1;
    }
    __syncthreads();

    // ---- H: output BN stats (4 weighted f64 sums) ---------------------------
    {
        double v4[4] = {0.0, 0.0, 0.0, 0.0};
        if (tid < 480) {
            const double n = (double)snn[tid];
            const double p0 = (double)spre0[tid], p1 = (double)spre1[tid];
            v4[0] = n * p0; v4[1] = n * p0 * p0; v4[2] = n * p1; v4[3] = n * p1 * p1;
        }
#pragma unroll
        for (int off = 32; off; off >>= 1)
#pragma unroll
            for (int s = 0; s < 4; ++s) v4[s] += __shfl_xor(v4[s], off);
        if (lane == 0)
#pragma unroll
            for (int s = 0; s < 4; ++s) wpart[w][s] = v4[s];
        __syncthreads();
        if (tid == 0) {
            double a[4] = {0.0, 0.0, 0.0, 0.0};
#pragma unroll
            for (int i = 0; i < 8; ++i)
#pragma unroll
                for (int s = 0; s < 4; ++s) a[s] += wpart[i][s];
#pragma unroll
            for (int s = 0; s < 4; ++s) dstat[2 + s] = a[s];
        }
        __syncthreads();
    }

    // ---- I: final output table (LDS) ----------------------------------------
    if (tid < 480) {
        const double m0 = dstat[2] / (3.0 * (double)CNT);
        const double v0 = dstat[3] / (3.0 * (double)CNT) - m0 * m0;
        const double m1 = dstat[4] / (3.0 * (double)CNT);
        const double v1 = dstat[5] / (3.0 * (double)CNT) - m1 * m1;
        const float sc0 = go[0] * rsqrtf((float)v0 + EPS);
        const float sc1 = go[1] * rsqrtf((float)v1 + EPS);
        tb[tid] = make_float2(sc0 * (spre0[tid] - (float)m0) + beo[0],
                              sc1 * (spre1[tid] - (float)m1) + beo[1]);
    }
    __syncthreads();

    // ---- J: stream this block's row from codes (8 positions/thread) ---------
    const int b = blockIdx.x;
    const uint4 cw = *(const uint4*)(codes + (size_t)b * SEQL + tid * 8);
    const uint cw4[4] = {cw.x, cw.y, cw.z, cw.w};
    union { float f[48]; float4 v[12]; } u;
#pragma unroll
    for (int r = 0; r < 8; ++r) {
        const uint code = (cw4[r >> 1] >> ((r & 1) * 16)) & 0xffffu;
        const int qd = (int)(code & 0xffu), qp = (int)(code >> 8);
        const float2 v0 = tb[qd], v1 = tb[NPAT + qd], v2 = tb[2 * NPAT + qp];
        u.f[r * 6 + 0] = v0.x; u.f[r * 6 + 1] = v0.y;
        u.f[r * 6 + 2] = v1.x; u.f[r * 6 + 3] = v1.y;
        u.f[r * 6 + 4] = v2.x; u.f[r * 6 + 5] = v2.y;
    }
    float4* o = (float4*)(out + ((size_t)b * SEQL + (size_t)tid * 8) * 6);
#pragma unroll
    for (int r = 0; r < 12; ++r) o[r] = u.v[r];
}

// =============================================================================
extern "C" void kernel_launch(void* const* d_in, const int* in_sizes, int n_in,
                              void* d_out, int out_size, void* d_ws, size_t ws_size,
                              hipStream_t stream) {
    (void)in_sizes; (void)n_in; (void)out_size; (void)ws_size;
    const float* x = (const float*)d_in[0];
    const int* perms = (const int*)d_in[1];

    PtrPack pk;
    for (int j = 0; j < 3; ++j)
        for (int s = 0; s < 6; ++s)
            pk.p[6 * j + s] = (const float*)d_in[2 + 6 * j + s];

    const float* Wm  = (const float*)d_in[20];
    const float* gm  = (const float*)d_in[22];
    const float* bem = (const float*)d_in[23];
    const float* Wo  = (const float*)d_in[24];
    const float* bo  = (const float*)d_in[25];
    const float* go  = (const float*)d_in[26];
    const float* beo = (const float*)d_in[27];

    // ws layout: [0, 320K) u32 part[320][256]; [320K, 320K+2M) u16 codes
    uint*     part  = (uint*)d_ws;
    ushort_t* codes = (ushort_t*)((char*)d_ws + 327680);

    k_prep<<<BATCH, 512, 0, stream>>>(x, perms, part, codes);
    k_mega<<<BATCH, 512, 0, stream>>>(pk, Wm, gm, bem, Wo, bo, go, beo,
                                      part, codes, (float*)d_out);
}

// Round 13
// 61.844 us; speedup vs baseline: 1.0396x; 1.0396x over previous
//
#include <hip/hip_runtime.h>
#include <hip/hip_bf16.h>
#include <math.h>

#define BATCH 256
#define SEQL  4096
#define DIMC  256
#define NPAT  160
#define CNT   (BATCH * SEQL)     // per-stream element count (over B,L)
#define EPS   1e-3f

typedef unsigned int uint;
typedef unsigned short ushort_t;

// ---------------- shared helpers ----------------------------------------------
__device__ __forceinline__ int pad_mask(int type) {
    return (type == 0) ? 0 : (type == 1) ? 3 : (type == 2) ? 1 : (type == 3) ? 16 : 24;
}

// tap value for extended-pattern q, index k in [0,6): k==5 is the constant 1.
__device__ __forceinline__ float tap6(int q, int k) {
    if (k == 5) return 1.0f;
    const int type = q >> 5, bits = q & 31;
    const int pm = pad_mask(type);
    if ((pm >> k) & 1) return 0.0f;
    return ((bits >> k) & 1) ? 1.0f : -1.0f;
}

__device__ __forceinline__ float fast_elu(float x) {
    return x > 0.0f ? x : (__expf(x) - 1.0f);
}

__device__ __forceinline__ int pat_type(int t) {
    if (t >= 2 && t < SEQL - 2) return 0;
    if (t == 0) return 1;
    if (t == 1) return 2;
    if (t == SEQL - 2) return 3;
    return 4;
}

struct PtrPack { const float* p[18]; };  // per stream: Wc, bc, g, be, Wf, bf

// =============================================================================
// k_prep: bit-pack rows (ballot), per-position codes, per-block partial hist
// (non-atomic transposed [bin][block] -> no zeroing kernel needed).
// 256 blocks x 512 threads.  [proven rounds 3/12]
// =============================================================================
__global__ __launch_bounds__(512) void k_prep(const float* __restrict__ x,
                                              const int* __restrict__ perms,
                                              uint* __restrict__ part,
                                              ushort_t* __restrict__ codes) {
    __shared__ uint xw[130];    // bit-packed row, 1-word zero sentinel each end
    __shared__ uint xwI[130];
    __shared__ uint h[2 * NPAT];
    const int b = blockIdx.x, tid = threadIdx.x;
    const int lane = tid & 63;

    for (int i = tid; i < 2 * NPAT; i += 512) h[i] = 0;
    if (tid < 2) { xw[tid * 129] = 0; xwI[tid * 129] = 0; }

    const float* xr = x + (size_t)b * SEQL;
    const int* pr = perms + (size_t)b * SEQL;

#pragma unroll
    for (int it = 0; it < 8; ++it) {
        const int i = it * 512 + tid;
        const unsigned long long m = __ballot(xr[i] > 0.5f);
        if (lane == 0) {
            const int w = 1 + ((it * 512 + (tid & ~63)) >> 5);
            xw[w] = (uint)m;
            xw[w + 1] = (uint)(m >> 32);
        }
    }
    __syncthreads();
#pragma unroll
    for (int it = 0; it < 8; ++it) {
        const int i = it * 512 + tid;
        const int p = pr[i];
        const unsigned long long m = __ballot(((xw[1 + (p >> 5)] >> (p & 31)) & 1u) != 0u);
        if (lane == 0) {
            const int w = 1 + ((it * 512 + (tid & ~63)) >> 5);
            xwI[w] = (uint)m;
            xwI[w + 1] = (uint)(m >> 32);
        }
    }
    __syncthreads();

    const int t0 = tid * 8;
    const int w = (t0 + 30) >> 5;
    const int sh0 = (t0 + 30) & 31;
    const unsigned long long Wd = (unsigned long long)xw[w] | ((unsigned long long)xw[w + 1] << 32);
    const unsigned long long Wi = (unsigned long long)xwI[w] | ((unsigned long long)xwI[w + 1] << 32);
    int c[8];
#pragma unroll
    for (int r = 0; r < 8; ++r) {
        const int t = t0 + r;
        const int type = pat_type(t);
        const int qd = type * 32 + (int)((Wd >> (sh0 + r)) & 31ull);
        const int qp = type * 32 + (int)((Wi >> (sh0 + r)) & 31ull);
        atomicAdd(&h[qd], 1u);
        atomicAdd(&h[NPAT + qp], 1u);
        c[r] = qd | (qp << 8);
    }
    uint4 cv;
    cv.x = (uint)(c[0] | (c[1] << 16));
    cv.y = (uint)(c[2] | (c[3] << 16));
    cv.z = (uint)(c[4] | (c[5] << 16));
    cv.w = (uint)(c[6] | (c[7] << 16));
    *(uint4*)(codes + (size_t)b * SEQL + t0) = cv;
    __syncthreads();

    if (tid < 2 * NPAT) part[(size_t)tid * 256 + b] = h[tid];
}

// =============================================================================
// k_etab3b: e-table, 480 blocks (one per (stream j, pattern q)) x 256 threads.
// Proven etab3 math; hist obtained by per-block reduce of the partials
// (L3-hot, latency hidden across 480 blocks).
// =============================================================================
__global__ __launch_bounds__(256) void k_etab3b(PtrPack pk,
                                                const uint* __restrict__ part,
                                                float* __restrict__ e_tab) {
    const int bid = blockIdx.x;           // 0..479
    const int j = bid / NPAT, q = bid % NPAT;
    const int c = threadIdx.x;            // channel
    const int lane = c & 63, w = c >> 6;  // 4 waves

    __shared__ float sh[NPAT];
    __shared__ float m6p[21][8];
    __shared__ float sM6[21];
    __shared__ float red[4];

    if (c < NPAT) {
        const uint4* pp = (const uint4*)(part + (size_t)((j == 2 ? NPAT : 0) + c) * 256);
        uint s = 0;
#pragma unroll 8
        for (int i = 0; i < 64; ++i) {
            const uint4 v = pp[i];
            s += v.x + v.y + v.z + v.w;
        }
        sh[c] = (float)s;
    }
    __syncthreads();

    // M6: 168 threads cover 21 entries x 8 chunks of 20 bins (static per thread)
    if (c < 168) {
        const int e = c >> 3, prt = c & 7;
        int k = 0, rem = e;
        while (rem > 5 - k) { rem -= 6 - k; ++k; }
        const int l = k + rem;
        float S = 0.0f;
        for (int qq = prt * 20; qq < prt * 20 + 20; ++qq)
            S += sh[qq] * tap6(qq, k) * tap6(qq, l);
        m6p[e][prt] = S;
    }
    __syncthreads();
    if (c < 21) {
        float S = 0.0f;
#pragma unroll
        for (int p = 0; p < 8; ++p) S += m6p[c][p];
        sM6[c] = S;
    }
    __syncthreads();

    // per-channel BN coefficients — entirely in registers, fully unrolled
    const float* Wc = pk.p[6 * j + 0];
    const float* bc = pk.p[6 * j + 1];
    const float* g  = pk.p[6 * j + 2];
    const float* be = pk.p[6 * j + 3];
    const float* Wf = pk.p[6 * j + 4];
    const float  bf = pk.p[6 * j + 5][0];

    float w6[6];
#pragma unroll
    for (int k = 0; k < 5; ++k) w6[k] = Wc[k * DIMC + c];
    w6[5] = bc[c];

    double Ey = 0.0, Ey2 = 0.0;
    {
        int e = 0;
#pragma unroll
        for (int k = 0; k < 6; ++k) {
#pragma unroll
            for (int l = k; l < 6; ++l, ++e) {
                const double p = (double)w6[k] * (double)w6[l] * (double)sM6[e];
                Ey2 += (l == k) ? p : 2.0 * p;
                if (l == 5) Ey += (double)w6[k] * (double)sM6[e];
            }
        }
    }
    const double mean = Ey / (double)CNT;
    const double var = Ey2 / (double)CNT - mean * mean;
    const float scale = g[c] * rsqrtf((float)var + EPS);

    float tk[5];
#pragma unroll
    for (int k = 0; k < 5; ++k) tk[k] = tap6(q, k);

    float bn = scale * (w6[5] - (float)mean) + be[c];
#pragma unroll
    for (int k = 0; k < 5; ++k) bn += tk[k] * (scale * w6[k]);
    float v = fast_elu(bn) * Wf[c];

#pragma unroll
    for (int off = 32; off; off >>= 1) v += __shfl_xor(v, off);
    if (lane == 0) red[w] = v;
    __syncthreads();
    if (c == 0) e_tab[bid] = red[0] + red[1] + red[2] + red[3] + bf;
}

// =============================================================================
// k_wfin2: 256 blocks x 512 threads. Per-block: reduce partials -> hist,
// redundant outtab finish with float4-packed coefficients (1 ds_read_b128
// per channel in the hot dot), final table in LDS, stream own row.
// =============================================================================
__global__ __launch_bounds__(512) void k_wfin2(const ushort_t* __restrict__ codes,
                                               const uint* __restrict__ part,
                                               const float* __restrict__ e_tab,
                                               const float* __restrict__ Wm,
                                               const float* __restrict__ gm,
                                               const float* __restrict__ bem,
                                               const float* __restrict__ Wo,
                                               const float* __restrict__ bo,
                                               const float* __restrict__ go,
                                               const float* __restrict__ beo,
                                               float* __restrict__ out) {
    const int tid = threadIdx.x;
    const int lane = tid & 63, w = tid >> 6;   // 8 waves

    __shared__ float sh_hist[2 * NPAT];
    __shared__ float se[480], snn[480], spre0[480], spre1[480];
    __shared__ float4 sFin[DIMC];              // {A, B, Wo0, Wo1}
    __shared__ float2 tb[480];
    __shared__ double wpart[8][4];
    __shared__ double dstat[6];

    // ---- A: reduce partials -> histogram (bin-per-thread, L3-hot) -----------
    if (tid < 2 * NPAT) {
        const uint4* pp = (const uint4*)(part + (size_t)tid * 256);
        uint s = 0;
#pragma unroll 8
        for (int i = 0; i < 64; ++i) {
            const uint4 v = pp[i];
            s += v.x + v.y + v.z + v.w;
        }
        sh_hist[tid] = (float)s;
    }
    __syncthreads();

    if (tid < 480) {
        se[tid] = e_tab[tid];
        snn[tid] = sh_hist[(tid >= 2 * NPAT) ? (tid - NPAT) : (tid % NPAT)];
    }
    __syncthreads();

    // ---- B: yt mean/var (weighted f64 over 480 bins) ------------------------
    {
        double d1 = 0.0, d2 = 0.0;
        if (tid < 480) {
            const double n = (double)snn[tid], e = (double)se[tid];
            d1 = n * e; d2 = n * e * e;
        }
#pragma unroll
        for (int off = 32; off; off >>= 1) {
            d1 += __shfl_xor(d1, off);
            d2 += __shfl_xor(d2, off);
        }
        if (lane == 0) { wpart[w][0] = d1; wpart[w][1] = d2; }
        __syncthreads();
        if (tid == 0) {
            double a = 0.0, b2 = 0.0;
#pragma unroll
            for (int i = 0; i < 8; ++i) { a += wpart[i][0]; b2 += wpart[i][1]; }
            dstat[0] = a; dstat[1] = b2;
        }
        __syncthreads();
    }
    const double mean_yt = dstat[0] / (3.0 * (double)CNT);
    const double var_yt  = dstat[1] / (3.0 * (double)CNT) - mean_yt * mean_yt;

    // ---- C: middle-unit affine coefficients (packed float4) -----------------
    if (tid < DIMC) {
        const float wm = Wm[tid];
        sFin[tid] = make_float4(
            gm[tid] * wm * rsqrtf(wm * wm * (float)var_yt + EPS),
            bem[tid],
            Wo[tid * 2 + 0],
            Wo[tid * 2 + 1]);
    }
    __syncthreads();

    // ---- D: pre-activations, ONE PATTERN PER THREAD, 1 b128/channel ---------
    if (tid < 480) {
        const float du = se[tid] - (float)mean_yt;
        float a0 = bo[0], a1 = bo[1];
#pragma unroll 4
        for (int c = 0; c < DIMC; ++c) {
            const float4 f = sFin[c];
            const float mo = fast_elu(f.x * du + f.y);
            a0 += mo * f.z;
            a1 += mo * f.w;
        }
        spre0[tid] = a0;
        spre1[tid] = a1;
    }
    __syncthreads();

    // ---- E: output BN stats (4 weighted f64 sums) ---------------------------
    {
        double v4[4] = {0.0, 0.0, 0.0, 0.0};
        if (tid < 480) {
            const double n = (double)snn[tid];
            const double p0 = (double)spre0[tid], p1 = (double)spre1[tid];
            v4[0] = n * p0; v4[1] = n * p0 * p0; v4[2] = n * p1; v4[3] = n * p1 * p1;
        }
#pragma unroll
        for (int off = 32; off; off >>= 1)
#pragma unroll
            for (int s = 0; s < 4; ++s) v4[s] += __shfl_xor(v4[s], off);
        if (lane == 0)
#pragma unroll
            for (int s = 0; s < 4; ++s) wpart[w][s] = v4[s];
        __syncthreads();
        if (tid == 0) {
            double a[4] = {0.0, 0.0, 0.0, 0.0};
#pragma unroll
            for (int i = 0; i < 8; ++i)
#pragma unroll
                for (int s = 0; s < 4; ++s) a[s] += wpart[i][s];
#pragma unroll
            for (int s = 0; s < 4; ++s) dstat[2 + s] = a[s];
        }
        __syncthreads();
    }

    // ---- F: final output table (LDS) ----------------------------------------
    if (tid < 480) {
        const double m0 = dstat[2] / (3.0 * (double)CNT);
        const double v0 = dstat[3] / (3.0 * (double)CNT) - m0 * m0;
        const double m1 = dstat[4] / (3.0 * (double)CNT);
        const double v1 = dstat[5] / (3.0 * (double)CNT) - m1 * m1;
        const float sc0 = go[0] * rsqrtf((float)v0 + EPS);
        const float sc1 = go[1] * rsqrtf((float)v1 + EPS);
        tb[tid] = make_float2(sc0 * (spre0[tid] - (float)m0) + beo[0],
                              sc1 * (spre1[tid] - (float)m1) + beo[1]);
    }
    __syncthreads();

    // ---- G: stream this block's row from codes (8 positions/thread) ---------
    const int b = blockIdx.x;
    const uint4 cw = *(const uint4*)(codes + (size_t)b * SEQL + tid * 8);
    const uint cw4[4] = {cw.x, cw.y, cw.z, cw.w};
    union { float f[48]; float4 v[12]; } u;
#pragma unroll
    for (int r = 0; r < 8; ++r) {
        const uint code = (cw4[r >> 1] >> ((r & 1) * 16)) & 0xffffu;
        const int qd = (int)(code & 0xffu), qp = (int)(code >> 8);
        const float2 v0 = tb[qd], v1 = tb[NPAT + qd], v2 = tb[2 * NPAT + qp];
        u.f[r * 6 + 0] = v0.x; u.f[r * 6 + 1] = v0.y;
        u.f[r * 6 + 2] = v1.x; u.f[r * 6 + 3] = v1.y;
        u.f[r * 6 + 4] = v2.x; u.f[r * 6 + 5] = v2.y;
    }
    float4* o = (float4*)(out + ((size_t)b * SEQL + (size_t)tid * 8) * 6);
#pragma unroll
    for (int r = 0; r < 12; ++r) o[r] = u.v[r];
}

// =============================================================================
extern "C" void kernel_launch(void* const* d_in, const int* in_sizes, int n_in,
                              void* d_out, int out_size, void* d_ws, size_t ws_size,
                              hipStream_t stream) {
    (void)in_sizes; (void)n_in; (void)out_size; (void)ws_size;
    const float* x = (const float*)d_in[0];
    const int* perms = (const int*)d_in[1];

    PtrPack pk;
    for (int j = 0; j < 3; ++j)
        for (int s = 0; s < 6; ++s)
            pk.p[6 * j + s] = (const float*)d_in[2 + 6 * j + s];

    const float* Wm  = (const float*)d_in[20];
    const float* gm  = (const float*)d_in[22];
    const float* bem = (const float*)d_in[23];
    const float* Wo  = (const float*)d_in[24];
    const float* bo  = (const float*)d_in[25];
    const float* go  = (const float*)d_in[26];
    const float* beo = (const float*)d_in[27];

    // ws layout: [0, 320K) u32 part[320][256]; [320K, 322K) f32 e_tab[480];
    //            [327680+4096, +2M) u16 codes
    uint*     part  = (uint*)d_ws;
    float*    e_tab = (float*)((char*)d_ws + 327680);
    ushort_t* codes = (ushort_t*)((char*)d_ws + 327680 + 4096);

    k_prep<<<BATCH, 512, 0, stream>>>(x, perms, part, codes);
    k_etab3b<<<480, 256, 0, stream>>>(pk, part, e_tab);
    k_wfin2<<<BATCH, 512, 0, stream>>>(codes, part, e_tab,
                                       Wm, gm, bem, Wo, bo, go, beo, (float*)d_out);
}

// Round 14
// 49.288 us; speedup vs baseline: 1.3044x; 1.2547x over previous
//
#include <hip/hip_runtime.h>
#include <hip/hip_bf16.h>
#include <math.h>

#define BATCH 256
#define SEQL  4096
#define DIMC  256
#define NPAT  160
#define CNT   (BATCH * SEQL)     // per-stream element count (over B,L)
#define EPS   1e-3f

typedef unsigned int uint;
typedef unsigned short ushort_t;

// ---------------- shared helpers ----------------------------------------------
__device__ __forceinline__ int pad_mask(int type) {
    return (type == 0) ? 0 : (type == 1) ? 3 : (type == 2) ? 1 : (type == 3) ? 16 : 24;
}

// tap value for extended-pattern q, index k in [0,6): k==5 is the constant 1.
__device__ __forceinline__ float tap6(int q, int k) {
    if (k == 5) return 1.0f;
    const int type = q >> 5, bits = q & 31;
    const int pm = pad_mask(type);
    if ((pm >> k) & 1) return 0.0f;
    return ((bits >> k) & 1) ? 1.0f : -1.0f;
}

__device__ __forceinline__ float fast_elu(float x) {
    return x > 0.0f ? x : (__expf(x) - 1.0f);
}

__device__ __forceinline__ int pat_type(int t) {
    if (t >= 2 && t < SEQL - 2) return 0;
    if (t == 0) return 1;
    if (t == 1) return 2;
    if (t == SEQL - 2) return 3;
    return 4;
}

struct PtrPack { const float* p[18]; };  // per stream: Wc, bc, g, be, Wf, bf

// =============================================================================
// k_zero: zero the 320-word histogram. [proven R11]
// =============================================================================
__global__ __launch_bounds__(320) void k_zero(uint* __restrict__ hist) {
    hist[threadIdx.x] = 0u;
}

// =============================================================================
// k_prep: bit-pack rows (ballot), per-position codes, LDS hist -> global
// atomic hist (1.3 KB total). 256 blocks x 512 threads.  [proven R11]
// =============================================================================
__global__ __launch_bounds__(512) void k_prep(const float* __restrict__ x,
                                              const int* __restrict__ perms,
                                              uint* __restrict__ hist,
                                              ushort_t* __restrict__ codes) {
    __shared__ uint xw[130];    // bit-packed row, 1-word zero sentinel each end
    __shared__ uint xwI[130];
    __shared__ uint h[2 * NPAT];
    const int b = blockIdx.x, tid = threadIdx.x;
    const int lane = tid & 63;

    for (int i = tid; i < 2 * NPAT; i += 512) h[i] = 0;
    if (tid < 2) { xw[tid * 129] = 0; xwI[tid * 129] = 0; }

    const float* xr = x + (size_t)b * SEQL;
    const int* pr = perms + (size_t)b * SEQL;

#pragma unroll
    for (int it = 0; it < 8; ++it) {
        const int i = it * 512 + tid;
        const unsigned long long m = __ballot(xr[i] > 0.5f);
        if (lane == 0) {
            const int w = 1 + ((it * 512 + (tid & ~63)) >> 5);
            xw[w] = (uint)m;
            xw[w + 1] = (uint)(m >> 32);
        }
    }
    __syncthreads();
#pragma unroll
    for (int it = 0; it < 8; ++it) {
        const int i = it * 512 + tid;
        const int p = pr[i];
        const unsigned long long m = __ballot(((xw[1 + (p >> 5)] >> (p & 31)) & 1u) != 0u);
        if (lane == 0) {
            const int w = 1 + ((it * 512 + (tid & ~63)) >> 5);
            xwI[w] = (uint)m;
            xwI[w + 1] = (uint)(m >> 32);
        }
    }
    __syncthreads();

    const int t0 = tid * 8;
    const int w = (t0 + 30) >> 5;
    const int sh0 = (t0 + 30) & 31;
    const unsigned long long Wd = (unsigned long long)xw[w] | ((unsigned long long)xw[w + 1] << 32);
    const unsigned long long Wi = (unsigned long long)xwI[w] | ((unsigned long long)xwI[w + 1] << 32);
    int c[8];
#pragma unroll
    for (int r = 0; r < 8; ++r) {
        const int t = t0 + r;
        const int type = pat_type(t);
        const int qd = type * 32 + (int)((Wd >> (sh0 + r)) & 31ull);
        const int qp = type * 32 + (int)((Wi >> (sh0 + r)) & 31ull);
        atomicAdd(&h[qd], 1u);
        atomicAdd(&h[NPAT + qp], 1u);
        c[r] = qd | (qp << 8);
    }
    uint4 cv;
    cv.x = (uint)(c[0] | (c[1] << 16));
    cv.y = (uint)(c[2] | (c[3] << 16));
    cv.z = (uint)(c[4] | (c[5] << 16));
    cv.w = (uint)(c[6] | (c[7] << 16));
    *(uint4*)(codes + (size_t)b * SEQL + t0) = cv;
    __syncthreads();

    if (tid < 2 * NPAT) {
        const uint v = h[tid];
        if (v) atomicAdd(&hist[tid], v);
    }
}

// =============================================================================
// k_etab3: e-table, 480 blocks (one per (stream j, pattern q)) x 256 threads.
// [proven R8/R11]
// =============================================================================
__global__ __launch_bounds__(256) void k_etab3(PtrPack pk,
                                               const uint* __restrict__ hist,
                                               float* __restrict__ e_tab) {
    const int bid = blockIdx.x;           // 0..479
    const int j = bid / NPAT, q = bid % NPAT;
    const int c = threadIdx.x;            // channel
    const int lane = c & 63, w = c >> 6;  // 4 waves

    __shared__ float sh[NPAT];
    __shared__ float m6p[21][8];
    __shared__ float sM6[21];
    __shared__ float red[4];

    if (c < NPAT) sh[c] = (float)hist[(j == 2 ? NPAT : 0) + c];
    __syncthreads();

    if (c < 168) {
        const int e = c >> 3, prt = c & 7;
        int k = 0, rem = e;
        while (rem > 5 - k) { rem -= 6 - k; ++k; }
        const int l = k + rem;
        float S = 0.0f;
        for (int qq = prt * 20; qq < prt * 20 + 20; ++qq)
            S += sh[qq] * tap6(qq, k) * tap6(qq, l);
        m6p[e][prt] = S;
    }
    __syncthreads();
    if (c < 21) {
        float S = 0.0f;
#pragma unroll
        for (int p = 0; p < 8; ++p) S += m6p[c][p];
        sM6[c] = S;
    }
    __syncthreads();

    const float* Wc = pk.p[6 * j + 0];
    const float* bc = pk.p[6 * j + 1];
    const float* g  = pk.p[6 * j + 2];
    const float* be = pk.p[6 * j + 3];
    const float* Wf = pk.p[6 * j + 4];
    const float  bf = pk.p[6 * j + 5][0];

    float w6[6];
#pragma unroll
    for (int k = 0; k < 5; ++k) w6[k] = Wc[k * DIMC + c];
    w6[5] = bc[c];

    double Ey = 0.0, Ey2 = 0.0;
    {
        int e = 0;
#pragma unroll
        for (int k = 0; k < 6; ++k) {
#pragma unroll
            for (int l = k; l < 6; ++l, ++e) {
                const double p = (double)w6[k] * (double)w6[l] * (double)sM6[e];
                Ey2 += (l == k) ? p : 2.0 * p;
                if (l == 5) Ey += (double)w6[k] * (double)sM6[e];
            }
        }
    }
    const double mean = Ey / (double)CNT;
    const double var = Ey2 / (double)CNT - mean * mean;
    const float scale = g[c] * rsqrtf((float)var + EPS);

    float tk[5];
#pragma unroll
    for (int k = 0; k < 5; ++k) tk[k] = tap6(q, k);

    float bn = scale * (w6[5] - (float)mean) + be[c];
#pragma unroll
    for (int k = 0; k < 5; ++k) bn += tk[k] * (scale * w6[k]);
    float v = fast_elu(bn) * Wf[c];

#pragma unroll
    for (int off = 32; off; off >>= 1) v += __shfl_xor(v, off);
    if (lane == 0) red[w] = v;
    __syncthreads();
    if (c == 0) e_tab[bid] = red[0] + red[1] + red[2] + red[3] + bf;
}

// =============================================================================
// k_wfin3: 256 blocks x 1024 threads. Redundant outtab finish with the
// channel-dot SPLIT across 2 threads per pattern (halved serial chain),
// float4-packed coefficients, then stream own row (4 positions/thread).
// =============================================================================
__global__ __launch_bounds__(1024) void k_wfin3(const ushort_t* __restrict__ codes,
                                                const uint* __restrict__ hist,
                                                const float* __restrict__ e_tab,
                                                const float* __restrict__ Wm,
                                                const float* __restrict__ gm,
                                                const float* __restrict__ bem,
                                                const float* __restrict__ Wo,
                                                const float* __restrict__ bo,
                                                const float* __restrict__ go,
                                                const float* __restrict__ beo,
                                                float* __restrict__ out) {
    const int tid = threadIdx.x;
    const int lane = tid & 63, w = tid >> 6;   // 16 waves

    __shared__ float se[480], snn[480];
    __shared__ float sp0h[2][480], sp1h[2][480];
    __shared__ float spre0[480], spre1[480];
    __shared__ float4 sFin[DIMC];              // {A, B, Wo0, Wo1}
    __shared__ float2 tb[480];
    __shared__ double wpart[16][4];
    __shared__ double dstat[6];

    // ---- A: load e-table + histogram (tiny, L2-hot) -------------------------
    if (tid < 480) {
        se[tid] = e_tab[tid];
        snn[tid] = (float)hist[(tid >= 2 * NPAT) ? (tid - NPAT) : (tid % NPAT)];
    }
    __syncthreads();

    // ---- B: yt mean/var (weighted f64 over 480 bins) ------------------------
    {
        double d1 = 0.0, d2 = 0.0;
        if (tid < 480) {
            const double n = (double)snn[tid], e = (double)se[tid];
            d1 = n * e; d2 = n * e * e;
        }
#pragma unroll
        for (int off = 32; off; off >>= 1) {
            d1 += __shfl_xor(d1, off);
            d2 += __shfl_xor(d2, off);
        }
        if (lane == 0) { wpart[w][0] = d1; wpart[w][1] = d2; }
        __syncthreads();
        if (tid == 0) {
            double a = 0.0, b2 = 0.0;
#pragma unroll
            for (int i = 0; i < 16; ++i) { a += wpart[i][0]; b2 += wpart[i][1]; }
            dstat[0] = a; dstat[1] = b2;
        }
        __syncthreads();
    }
    const double mean_yt = dstat[0] / (3.0 * (double)CNT);
    const double var_yt  = dstat[1] / (3.0 * (double)CNT) - mean_yt * mean_yt;

    // ---- C: middle-unit affine coefficients (packed float4) -----------------
    if (tid < DIMC) {
        const float wm = Wm[tid];
        sFin[tid] = make_float4(
            gm[tid] * wm * rsqrtf(wm * wm * (float)var_yt + EPS),
            bem[tid],
            Wo[tid * 2 + 0],
            Wo[tid * 2 + 1]);
    }
    __syncthreads();

    // ---- D: pre-activations, 2 THREADS PER PATTERN (128 channels each) ------
    {
        const int half = tid >> 9;       // 0 or 1
        const int p = tid & 511;
        if (p < 480) {
            const float du = se[p] - (float)mean_yt;
            float a0 = 0.0f, a1 = 0.0f;
            const int c0 = half * 128;
#pragma unroll 4
            for (int c = c0; c < c0 + 128; ++c) {
                const float4 f = sFin[c];
                const float mo = fast_elu(f.x * du + f.y);
                a0 += mo * f.z;
                a1 += mo * f.w;
            }
            sp0h[half][p] = a0;
            sp1h[half][p] = a1;
        }
    }
    __syncthreads();
    if (tid < 480) {
        spre0[tid] = sp0h[0][tid] + sp0h[1][tid] + bo[0];
        spre1[tid] = sp1h[0][tid] + sp1h[1][tid] + bo[1];
    }
    __syncthreads();

    // ---- E: output BN stats (4 weighted f64 sums) ---------------------------
    {
        double v4[4] = {0.0, 0.0, 0.0, 0.0};
        if (tid < 480) {
            const double n = (double)snn[tid];
            const double p0 = (double)spre0[tid], p1 = (double)spre1[tid];
            v4[0] = n * p0; v4[1] = n * p0 * p0; v4[2] = n * p1; v4[3] = n * p1 * p1;
        }
#pragma unroll
        for (int off = 32; off; off >>= 1)
#pragma unroll
            for (int s = 0; s < 4; ++s) v4[s] += __shfl_xor(v4[s], off);
        if (lane == 0)
#pragma unroll
            for (int s = 0; s < 4; ++s) wpart[w][s] = v4[s];
        __syncthreads();
        if (tid == 0) {
            double a[4] = {0.0, 0.0, 0.0, 0.0};
#pragma unroll
            for (int i = 0; i < 16; ++i)
#pragma unroll
                for (int s = 0; s < 4; ++s) a[s] += wpart[i][s];
#pragma unroll
            for (int s = 0; s < 4; ++s) dstat[2 + s] = a[s];
        }
        __syncthreads();
    }

    // ---- F: final output table (LDS) ----------------------------------------
    if (tid < 480) {
        const double m0 = dstat[2] / (3.0 * (double)CNT);
        const double v0 = dstat[3] / (3.0 * (double)CNT) - m0 * m0;
        const double m1 = dstat[4] / (3.0 * (double)CNT);
        const double v1 = dstat[5] / (3.0 * (double)CNT) - m1 * m1;
        const float sc0 = go[0] * rsqrtf((float)v0 + EPS);
        const float sc1 = go[1] * rsqrtf((float)v1 + EPS);
        tb[tid] = make_float2(sc0 * (spre0[tid] - (float)m0) + beo[0],
                              sc1 * (spre1[tid] - (float)m1) + beo[1]);
    }
    __syncthreads();

    // ---- G: stream this block's row from codes (4 positions/thread) ---------
    const int b = blockIdx.x;
    const uint2 cw = *(const uint2*)(codes + (size_t)b * SEQL + tid * 4);
    const uint cw2[2] = {cw.x, cw.y};
    union { float f[24]; float4 v[6]; } u;
#pragma unroll
    for (int r = 0; r < 4; ++r) {
        const uint code = (cw2[r >> 1] >> ((r & 1) * 16)) & 0xffffu;
        const int qd = (int)(code & 0xffu), qp = (int)(code >> 8);
        const float2 v0 = tb[qd], v1 = tb[NPAT + qd], v2 = tb[2 * NPAT + qp];
        u.f[r * 6 + 0] = v0.x; u.f[r * 6 + 1] = v0.y;
        u.f[r * 6 + 2] = v1.x; u.f[r * 6 + 3] = v1.y;
        u.f[r * 6 + 4] = v2.x; u.f[r * 6 + 5] = v2.y;
    }
    float4* o = (float4*)(out + ((size_t)b * SEQL + (size_t)tid * 4) * 6);
#pragma unroll
    for (int r = 0; r < 6; ++r) o[r] = u.v[r];
}

// =============================================================================
extern "C" void kernel_launch(void* const* d_in, const int* in_sizes, int n_in,
                              void* d_out, int out_size, void* d_ws, size_t ws_size,
                              hipStream_t stream) {
    (void)in_sizes; (void)n_in; (void)out_size; (void)ws_size;
    const float* x = (const float*)d_in[0];
    const int* perms = (const int*)d_in[1];

    PtrPack pk;
    for (int j = 0; j < 3; ++j)
        for (int s = 0; s < 6; ++s)
            pk.p[6 * j + s] = (const float*)d_in[2 + 6 * j + s];

    const float* Wm  = (const float*)d_in[20];
    const float* gm  = (const float*)d_in[22];
    const float* bem = (const float*)d_in[23];
    const float* Wo  = (const float*)d_in[24];
    const float* bo  = (const float*)d_in[25];
    const float* go  = (const float*)d_in[26];
    const float* beo = (const float*)d_in[27];

    // ws layout: [0,1280) u32 hist[320]; [5632,7552) f32 e_tab[480];
    //            [8192, 8192+2M) u16 codes
    uint*     hist  = (uint*)d_ws;
    float*    e_tab = (float*)((char*)d_ws + 5632);
    ushort_t* codes = (ushort_t*)((char*)d_ws + 8192);

    k_zero<<<1, 320, 0, stream>>>(hist);
    k_prep<<<BATCH, 512, 0, stream>>>(x, perms, hist, codes);
    k_etab3<<<480, 256, 0, stream>>>(pk, hist, e_tab);
    k_wfin3<<<BATCH, 1024, 0, stream>>>(codes, hist, e_tab,
                                        Wm, gm, bem, Wo, bo, go, beo, (float*)d_out);
}

// Round 15
// 42.988 us; speedup vs baseline: 1.4956x; 1.1466x over previous
//
#include <hip/hip_runtime.h>
#include <hip/hip_bf16.h>
#include <math.h>

#define BATCH 256
#define SEQL  4096
#define DIMC  256
#define NPAT  160
#define CNT   (BATCH * SEQL)     // per-stream element count (over B,L)
#define EPS   1e-3f

typedef unsigned int uint;
typedef unsigned short ushort_t;

// ---------------- shared helpers ----------------------------------------------
__device__ __forceinline__ int pad_mask(int type) {
    return (type == 0) ? 0 : (type == 1) ? 3 : (type == 2) ? 1 : (type == 3) ? 16 : 24;
}

// tap value for extended-pattern q, index k in [0,6): k==5 is the constant 1.
__device__ __forceinline__ float tap6(int q, int k) {
    if (k == 5) return 1.0f;
    const int type = q >> 5, bits = q & 31;
    const int pm = pad_mask(type);
    if ((pm >> k) & 1) return 0.0f;
    return ((bits >> k) & 1) ? 1.0f : -1.0f;
}

__device__ __forceinline__ float fast_elu(float x) {
    return x > 0.0f ? x : (__expf(x) - 1.0f);
}

__device__ __forceinline__ int pat_type(int t) {
    if (t >= 2 && t < SEQL - 2) return 0;
    if (t == 0) return 1;
    if (t == 1) return 2;
    if (t == SEQL - 2) return 3;
    return 4;
}

struct PtrPack { const float* p[18]; };  // per stream: Wc, bc, g, be, Wf, bf

// =============================================================================
// k_zero: zero the 320-word histogram. [proven]
// =============================================================================
__global__ __launch_bounds__(320) void k_zero(uint* __restrict__ hist) {
    hist[threadIdx.x] = 0u;
}

// =============================================================================
// k_prep: bit-pack rows (ballot), per-position codes, LDS hist -> global
// atomic hist (1.3 KB total). 256 blocks x 512 threads.  [proven]
// =============================================================================
__global__ __launch_bounds__(512) void k_prep(const float* __restrict__ x,
                                              const int* __restrict__ perms,
                                              uint* __restrict__ hist,
                                              ushort_t* __restrict__ codes) {
    __shared__ uint xw[130];    // bit-packed row, 1-word zero sentinel each end
    __shared__ uint xwI[130];
    __shared__ uint h[2 * NPAT];
    const int b = blockIdx.x, tid = threadIdx.x;
    const int lane = tid & 63;

    for (int i = tid; i < 2 * NPAT; i += 512) h[i] = 0;
    if (tid < 2) { xw[tid * 129] = 0; xwI[tid * 129] = 0; }

    const float* xr = x + (size_t)b * SEQL;
    const int* pr = perms + (size_t)b * SEQL;

#pragma unroll
    for (int it = 0; it < 8; ++it) {
        const int i = it * 512 + tid;
        const unsigned long long m = __ballot(xr[i] > 0.5f);
        if (lane == 0) {
            const int w = 1 + ((it * 512 + (tid & ~63)) >> 5);
            xw[w] = (uint)m;
            xw[w + 1] = (uint)(m >> 32);
        }
    }
    __syncthreads();
#pragma unroll
    for (int it = 0; it < 8; ++it) {
        const int i = it * 512 + tid;
        const int p = pr[i];
        const unsigned long long m = __ballot(((xw[1 + (p >> 5)] >> (p & 31)) & 1u) != 0u);
        if (lane == 0) {
            const int w = 1 + ((it * 512 + (tid & ~63)) >> 5);
            xwI[w] = (uint)m;
            xwI[w + 1] = (uint)(m >> 32);
        }
    }
    __syncthreads();

    const int t0 = tid * 8;
    const int w = (t0 + 30) >> 5;
    const int sh0 = (t0 + 30) & 31;
    const unsigned long long Wd = (unsigned long long)xw[w] | ((unsigned long long)xw[w + 1] << 32);
    const unsigned long long Wi = (unsigned long long)xwI[w] | ((unsigned long long)xwI[w + 1] << 32);
    int c[8];
#pragma unroll
    for (int r = 0; r < 8; ++r) {
        const int t = t0 + r;
        const int type = pat_type(t);
        const int qd = type * 32 + (int)((Wd >> (sh0 + r)) & 31ull);
        const int qp = type * 32 + (int)((Wi >> (sh0 + r)) & 31ull);
        atomicAdd(&h[qd], 1u);
        atomicAdd(&h[NPAT + qp], 1u);
        c[r] = qd | (qp << 8);
    }
    uint4 cv;
    cv.x = (uint)(c[0] | (c[1] << 16));
    cv.y = (uint)(c[2] | (c[3] << 16));
    cv.z = (uint)(c[4] | (c[5] << 16));
    cv.w = (uint)(c[6] | (c[7] << 16));
    *(uint4*)(codes + (size_t)b * SEQL + t0) = cv;
    __syncthreads();

    if (tid < 2 * NPAT) {
        const uint v = h[tid];
        if (v) atomicAdd(&hist[tid], v);
    }
}

// =============================================================================
// k_etab3: e-table, 480 blocks (one per (stream j, pattern q)) x 256 threads.
// [proven]
// =============================================================================
__global__ __launch_bounds__(256) void k_etab3(PtrPack pk,
                                               const uint* __restrict__ hist,
                                               float* __restrict__ e_tab) {
    const int bid = blockIdx.x;           // 0..479
    const int j = bid / NPAT, q = bid % NPAT;
    const int c = threadIdx.x;            // channel
    const int lane = c & 63, w = c >> 6;  // 4 waves

    __shared__ float sh[NPAT];
    __shared__ float m6p[21][8];
    __shared__ float sM6[21];
    __shared__ float red[4];

    if (c < NPAT) sh[c] = (float)hist[(j == 2 ? NPAT : 0) + c];
    __syncthreads();

    if (c < 168) {
        const int e = c >> 3, prt = c & 7;
        int k = 0, rem = e;
        while (rem > 5 - k) { rem -= 6 - k; ++k; }
        const int l = k + rem;
        float S = 0.0f;
        for (int qq = prt * 20; qq < prt * 20 + 20; ++qq)
            S += sh[qq] * tap6(qq, k) * tap6(qq, l);
        m6p[e][prt] = S;
    }
    __syncthreads();
    if (c < 21) {
        float S = 0.0f;
#pragma unroll
        for (int p = 0; p < 8; ++p) S += m6p[c][p];
        sM6[c] = S;
    }
    __syncthreads();

    const float* Wc = pk.p[6 * j + 0];
    const float* bc = pk.p[6 * j + 1];
    const float* g  = pk.p[6 * j + 2];
    const float* be = pk.p[6 * j + 3];
    const float* Wf = pk.p[6 * j + 4];
    const float  bf = pk.p[6 * j + 5][0];

    float w6[6];
#pragma unroll
    for (int k = 0; k < 5; ++k) w6[k] = Wc[k * DIMC + c];
    w6[5] = bc[c];

    double Ey = 0.0, Ey2 = 0.0;
    {
        int e = 0;
#pragma unroll
        for (int k = 0; k < 6; ++k) {
#pragma unroll
            for (int l = k; l < 6; ++l, ++e) {
                const double p = (double)w6[k] * (double)w6[l] * (double)sM6[e];
                Ey2 += (l == k) ? p : 2.0 * p;
                if (l == 5) Ey += (double)w6[k] * (double)sM6[e];
            }
        }
    }
    const double mean = Ey / (double)CNT;
    const double var = Ey2 / (double)CNT - mean * mean;
    const float scale = g[c] * rsqrtf((float)var + EPS);

    float tk[5];
#pragma unroll
    for (int k = 0; k < 5; ++k) tk[k] = tap6(q, k);

    float bn = scale * (w6[5] - (float)mean) + be[c];
#pragma unroll
    for (int k = 0; k < 5; ++k) bn += tk[k] * (scale * w6[k]);
    float v = fast_elu(bn) * Wf[c];

#pragma unroll
    for (int off = 32; off; off >>= 1) v += __shfl_xor(v, off);
    if (lane == 0) red[w] = v;
    __syncthreads();
    if (c == 0) e_tab[bid] = red[0] + red[1] + red[2] + red[3] + bf;
}

// =============================================================================
// k_ytstat: 1 block x 512. Weighted yt mean/var over the 480 bins only.
// Short serial chains; writes yt[2] = {mean, var} as float.
// =============================================================================
__global__ __launch_bounds__(512) void k_ytstat(const uint* __restrict__ hist,
                                                const float* __restrict__ e_tab,
                                                float* __restrict__ yt) {
    const int tid = threadIdx.x;
    const int lane = tid & 63, w = tid >> 6;   // 8 waves
    __shared__ double wpart[8][2];

    double d1 = 0.0, d2 = 0.0;
    if (tid < 480) {
        const double n = (double)hist[(tid >= 2 * NPAT) ? (tid - NPAT) : (tid % NPAT)];
        const double e = (double)e_tab[tid];
        d1 = n * e; d2 = n * e * e;
    }
#pragma unroll
    for (int off = 32; off; off >>= 1) {
        d1 += __shfl_xor(d1, off);
        d2 += __shfl_xor(d2, off);
    }
    if (lane == 0) { wpart[w][0] = d1; wpart[w][1] = d2; }
    __syncthreads();
    if (tid == 0) {
        double a = 0.0, b2 = 0.0;
#pragma unroll
        for (int i = 0; i < 8; ++i) { a += wpart[i][0]; b2 += wpart[i][1]; }
        const double mean = a / (3.0 * (double)CNT);
        const double var = b2 / (3.0 * (double)CNT) - mean * mean;
        yt[0] = (float)mean;
        yt[1] = (float)var;
    }
}

// =============================================================================
// k_pre: 480 blocks (one per pattern) x 256 threads (one per channel).
// Middle+output unit pre-activations, coefficients in registers (etab3 shape).
// =============================================================================
__global__ __launch_bounds__(256) void k_pre(const float* __restrict__ e_tab,
                                             const float* __restrict__ yt,
                                             const float* __restrict__ Wm,
                                             const float* __restrict__ gm,
                                             const float* __restrict__ bem,
                                             const float* __restrict__ Wo,
                                             const float* __restrict__ bo,
                                             float* __restrict__ spre0,
                                             float* __restrict__ spre1) {
    const int p = blockIdx.x;             // pattern 0..479
    const int c = threadIdx.x;            // channel
    const int lane = c & 63, w = c >> 6;  // 4 waves
    __shared__ float red[4][2];

    const float var_yt = yt[1];
    const float du = e_tab[p] - yt[0];

    const float wm = Wm[c];
    const float A = gm[c] * wm * rsqrtf(wm * wm * var_yt + EPS);
    const float mo = fast_elu(A * du + bem[c]);
    float a0 = mo * Wo[c * 2 + 0];
    float a1 = mo * Wo[c * 2 + 1];

#pragma unroll
    for (int off = 32; off; off >>= 1) {
        a0 += __shfl_xor(a0, off);
        a1 += __shfl_xor(a1, off);
    }
    if (lane == 0) { red[w][0] = a0; red[w][1] = a1; }
    __syncthreads();
    if (c == 0) {
        spre0[p] = red[0][0] + red[1][0] + red[2][0] + red[3][0] + bo[0];
        spre1[p] = red[0][1] + red[1][1] + red[2][1] + red[3][1] + bo[1];
    }
}

// =============================================================================
// k_wfin5: 256 blocks x 512 threads. Light finish (out-stats + table) +
// stream own row. Codes prefetched at kernel entry (hidden under finish).
// =============================================================================
__global__ __launch_bounds__(512) void k_wfin5(const ushort_t* __restrict__ codes,
                                               const uint* __restrict__ hist,
                                               const float* __restrict__ spre0,
                                               const float* __restrict__ spre1,
                                               const float* __restrict__ go,
                                               const float* __restrict__ beo,
                                               float* __restrict__ out) {
    const int tid = threadIdx.x;
    const int lane = tid & 63, w = tid >> 6;   // 8 waves
    const int b = blockIdx.x;

    __shared__ float sp0[480], sp1[480], snn[480];
    __shared__ float2 tb[480];
    __shared__ double wpart[8][4];
    __shared__ double dstat[4];

    // prefetch this thread's codes early (use is after several barriers)
    const uint4 cw = *(const uint4*)(codes + (size_t)b * SEQL + tid * 8);

    if (tid < 480) {
        sp0[tid] = spre0[tid];
        sp1[tid] = spre1[tid];
        snn[tid] = (float)hist[(tid >= 2 * NPAT) ? (tid - NPAT) : (tid % NPAT)];
    }
    __syncthreads();

    // out-stats: 4 weighted f64 sums over 480 bins
    {
        double v4[4] = {0.0, 0.0, 0.0, 0.0};
        if (tid < 480) {
            const double n = (double)snn[tid];
            const double p0 = (double)sp0[tid], p1 = (double)sp1[tid];
            v4[0] = n * p0; v4[1] = n * p0 * p0; v4[2] = n * p1; v4[3] = n * p1 * p1;
        }
#pragma unroll
        for (int off = 32; off; off >>= 1)
#pragma unroll
            for (int s = 0; s < 4; ++s) v4[s] += __shfl_xor(v4[s], off);
        if (lane == 0)
#pragma unroll
            for (int s = 0; s < 4; ++s) wpart[w][s] = v4[s];
        __syncthreads();
        if (tid == 0) {
            double a[4] = {0.0, 0.0, 0.0, 0.0};
#pragma unroll
            for (int i = 0; i < 8; ++i)
#pragma unroll
                for (int s = 0; s < 4; ++s) a[s] += wpart[i][s];
#pragma unroll
            for (int s = 0; s < 4; ++s) dstat[s] = a[s];
        }
        __syncthreads();
    }

    // final output table (LDS)
    if (tid < 480) {
        const double m0 = dstat[0] / (3.0 * (double)CNT);
        const double v0 = dstat[1] / (3.0 * (double)CNT) - m0 * m0;
        const double m1 = dstat[2] / (3.0 * (double)CNT);
        const double v1 = dstat[3] / (3.0 * (double)CNT) - m1 * m1;
        const float sc0 = go[0] * rsqrtf((float)v0 + EPS);
        const float sc1 = go[1] * rsqrtf((float)v1 + EPS);
        tb[tid] = make_float2(sc0 * (sp0[tid] - (float)m0) + beo[0],
                              sc1 * (sp1[tid] - (float)m1) + beo[1]);
    }
    __syncthreads();

    // stream this block's row (8 positions/thread)
    const uint cw4[4] = {cw.x, cw.y, cw.z, cw.w};
    union { float f[48]; float4 v[12]; } u;
#pragma unroll
    for (int r = 0; r < 8; ++r) {
        const uint code = (cw4[r >> 1] >> ((r & 1) * 16)) & 0xffffu;
        const int qd = (int)(code & 0xffu), qp = (int)(code >> 8);
        const float2 v0 = tb[qd], v1 = tb[NPAT + qd], v2 = tb[2 * NPAT + qp];
        u.f[r * 6 + 0] = v0.x; u.f[r * 6 + 1] = v0.y;
        u.f[r * 6 + 2] = v1.x; u.f[r * 6 + 3] = v1.y;
        u.f[r * 6 + 4] = v2.x; u.f[r * 6 + 5] = v2.y;
    }
    float4* o = (float4*)(out + ((size_t)b * SEQL + (size_t)tid * 8) * 6);
#pragma unroll
    for (int r = 0; r < 12; ++r) o[r] = u.v[r];
}

// =============================================================================
extern "C" void kernel_launch(void* const* d_in, const int* in_sizes, int n_in,
                              void* d_out, int out_size, void* d_ws, size_t ws_size,
                              hipStream_t stream) {
    (void)in_sizes; (void)n_in; (void)out_size; (void)ws_size;
    const float* x = (const float*)d_in[0];
    const int* perms = (const int*)d_in[1];

    PtrPack pk;
    for (int j = 0; j < 3; ++j)
        for (int s = 0; s < 6; ++s)
            pk.p[6 * j + s] = (const float*)d_in[2 + 6 * j + s];

    const float* Wm  = (const float*)d_in[20];
    const float* gm  = (const float*)d_in[22];
    const float* bem = (const float*)d_in[23];
    const float* Wo  = (const float*)d_in[24];
    const float* bo  = (const float*)d_in[25];
    const float* go  = (const float*)d_in[26];
    const float* beo = (const float*)d_in[27];

    // ws layout: [0,1280) u32 hist[320]; [1280,1288) f32 yt[2];
    //            [1536,3456) f32 spre0[480]; [3456,5376) f32 spre1[480];
    //            [5632,7552) f32 e_tab[480]; [8192, 8192+2M) u16 codes
    uint*     hist  = (uint*)d_ws;
    float*    yt    = (float*)((char*)d_ws + 1280);
    float*    spre0 = (float*)((char*)d_ws + 1536);
    float*    spre1 = (float*)((char*)d_ws + 3456);
    float*    e_tab = (float*)((char*)d_ws + 5632);
    ushort_t* codes = (ushort_t*)((char*)d_ws + 8192);

    k_zero<<<1, 320, 0, stream>>>(hist);
    k_prep<<<BATCH, 512, 0, stream>>>(x, perms, hist, codes);
    k_etab3<<<480, 256, 0, stream>>>(pk, hist, e_tab);
    k_ytstat<<<1, 512, 0, stream>>>(hist, e_tab, yt);
    k_pre<<<480, 256, 0, stream>>>(e_tab, yt, Wm, gm, bem, Wo, bo, spre0, spre1);
    k_wfin5<<<BATCH, 512, 0, stream>>>(codes, hist, spre0, spre1, go, beo,
                                       (float*)d_out);
}

// Round 16
// 38.003 us; speedup vs baseline: 1.6918x; 1.1312x over previous
//
#include <hip/hip_runtime.h>
#include <hip/hip_bf16.h>
#include <math.h>

#define BATCH 256
#define SEQL  4096
#define DIMC  256
#define NPAT  160
#define CNT   (BATCH * SEQL)     // per-stream element count (over B,L)
#define EPS   1e-3f

typedef unsigned int uint;
typedef unsigned short ushort_t;

// ---------------- shared helpers ----------------------------------------------
__device__ __forceinline__ int pad_mask(int type) {
    return (type == 0) ? 0 : (type == 1) ? 3 : (type == 2) ? 1 : (type == 3) ? 16 : 24;
}

// tap value for extended-pattern q, index k in [0,6): k==5 is the constant 1.
__device__ __forceinline__ float tap6(int q, int k) {
    if (k == 5) return 1.0f;
    const int type = q >> 5, bits = q & 31;
    const int pm = pad_mask(type);
    if ((pm >> k) & 1) return 0.0f;
    return ((bits >> k) & 1) ? 1.0f : -1.0f;
}

__device__ __forceinline__ float fast_elu(float x) {
    return x > 0.0f ? x : (__expf(x) - 1.0f);
}

__device__ __forceinline__ int pat_type(int t) {
    if (t >= 2 && t < SEQL - 2) return 0;
    if (t == 0) return 1;
    if (t == 1) return 2;
    if (t == SEQL - 2) return 3;
    return 4;
}

struct PtrPack { const float* p[18]; };  // per stream: Wc, bc, g, be, Wf, bf

// =============================================================================
// k_prep: bit-pack rows (ballot), per-position codes, per-block partial hist
// (non-atomic transposed [bin][block] -> no zero kernel needed). [proven]
// =============================================================================
__global__ __launch_bounds__(512) void k_prep(const float* __restrict__ x,
                                              const int* __restrict__ perms,
                                              uint* __restrict__ part,
                                              ushort_t* __restrict__ codes) {
    __shared__ uint xw[130];    // bit-packed row, 1-word zero sentinel each end
    __shared__ uint xwI[130];
    __shared__ uint h[2 * NPAT];
    const int b = blockIdx.x, tid = threadIdx.x;
    const int lane = tid & 63;

    for (int i = tid; i < 2 * NPAT; i += 512) h[i] = 0;
    if (tid < 2) { xw[tid * 129] = 0; xwI[tid * 129] = 0; }

    const float* xr = x + (size_t)b * SEQL;
    const int* pr = perms + (size_t)b * SEQL;

#pragma unroll
    for (int it = 0; it < 8; ++it) {
        const int i = it * 512 + tid;
        const unsigned long long m = __ballot(xr[i] > 0.5f);
        if (lane == 0) {
            const int w = 1 + ((it * 512 + (tid & ~63)) >> 5);
            xw[w] = (uint)m;
            xw[w + 1] = (uint)(m >> 32);
        }
    }
    __syncthreads();
#pragma unroll
    for (int it = 0; it < 8; ++it) {
        const int i = it * 512 + tid;
        const int p = pr[i];
        const unsigned long long m = __ballot(((xw[1 + (p >> 5)] >> (p & 31)) & 1u) != 0u);
        if (lane == 0) {
            const int w = 1 + ((it * 512 + (tid & ~63)) >> 5);
            xwI[w] = (uint)m;
            xwI[w + 1] = (uint)(m >> 32);
        }
    }
    __syncthreads();

    const int t0 = tid * 8;
    const int w = (t0 + 30) >> 5;
    const int sh0 = (t0 + 30) & 31;
    const unsigned long long Wd = (unsigned long long)xw[w] | ((unsigned long long)xw[w + 1] << 32);
    const unsigned long long Wi = (unsigned long long)xwI[w] | ((unsigned long long)xwI[w + 1] << 32);
    int c[8];
#pragma unroll
    for (int r = 0; r < 8; ++r) {
        const int t = t0 + r;
        const int type = pat_type(t);
        const int qd = type * 32 + (int)((Wd >> (sh0 + r)) & 31ull);
        const int qp = type * 32 + (int)((Wi >> (sh0 + r)) & 31ull);
        atomicAdd(&h[qd], 1u);
        atomicAdd(&h[NPAT + qp], 1u);
        c[r] = qd | (qp << 8);
    }
    uint4 cv;
    cv.x = (uint)(c[0] | (c[1] << 16));
    cv.y = (uint)(c[2] | (c[3] << 16));
    cv.z = (uint)(c[4] | (c[5] << 16));
    cv.w = (uint)(c[6] | (c[7] << 16));
    *(uint4*)(codes + (size_t)b * SEQL + t0) = cv;
    __syncthreads();

    if (tid < 2 * NPAT) part[(size_t)tid * 256 + b] = h[tid];
}

// =============================================================================
// k_hred: 320 blocks x 64 threads — bin-per-block reduce of the partials.
// Distributed replacement for zeroing+atomics.
// =============================================================================
__global__ __launch_bounds__(64) void k_hred(const uint* __restrict__ part,
                                             uint* __restrict__ hist) {
    const int bin = blockIdx.x, lane = threadIdx.x;
    const uint4 v = *(const uint4*)(part + (size_t)bin * 256 + lane * 4);
    uint s = v.x + v.y + v.z + v.w;
#pragma unroll
    for (int off = 32; off; off >>= 1) s += __shfl_xor(s, off);
    if (lane == 0) hist[bin] = s;
}

// =============================================================================
// k_etab3: e-table, 480 blocks (one per (stream j, pattern q)) x 256 threads.
// [proven]
// =============================================================================
__global__ __launch_bounds__(256) void k_etab3(PtrPack pk,
                                               const uint* __restrict__ hist,
                                               float* __restrict__ e_tab) {
    const int bid = blockIdx.x;           // 0..479
    const int j = bid / NPAT, q = bid % NPAT;
    const int c = threadIdx.x;            // channel
    const int lane = c & 63, w = c >> 6;  // 4 waves

    __shared__ float sh[NPAT];
    __shared__ float m6p[21][8];
    __shared__ float sM6[21];
    __shared__ float red[4];

    if (c < NPAT) sh[c] = (float)hist[(j == 2 ? NPAT : 0) + c];
    __syncthreads();

    if (c < 168) {
        const int e = c >> 3, prt = c & 7;
        int k = 0, rem = e;
        while (rem > 5 - k) { rem -= 6 - k; ++k; }
        const int l = k + rem;
        float S = 0.0f;
        for (int qq = prt * 20; qq < prt * 20 + 20; ++qq)
            S += sh[qq] * tap6(qq, k) * tap6(qq, l);
        m6p[e][prt] = S;
    }
    __syncthreads();
    if (c < 21) {
        float S = 0.0f;
#pragma unroll
        for (int p = 0; p < 8; ++p) S += m6p[c][p];
        sM6[c] = S;
    }
    __syncthreads();

    const float* Wc = pk.p[6 * j + 0];
    const float* bc = pk.p[6 * j + 1];
    const float* g  = pk.p[6 * j + 2];
    const float* be = pk.p[6 * j + 3];
    const float* Wf = pk.p[6 * j + 4];
    const float  bf = pk.p[6 * j + 5][0];

    float w6[6];
#pragma unroll
    for (int k = 0; k < 5; ++k) w6[k] = Wc[k * DIMC + c];
    w6[5] = bc[c];

    double Ey = 0.0, Ey2 = 0.0;
    {
        int e = 0;
#pragma unroll
        for (int k = 0; k < 6; ++k) {
#pragma unroll
            for (int l = k; l < 6; ++l, ++e) {
                const double p = (double)w6[k] * (double)w6[l] * (double)sM6[e];
                Ey2 += (l == k) ? p : 2.0 * p;
                if (l == 5) Ey += (double)w6[k] * (double)sM6[e];
            }
        }
    }
    const double mean = Ey / (double)CNT;
    const double var = Ey2 / (double)CNT - mean * mean;
    const float scale = g[c] * rsqrtf((float)var + EPS);

    float tk[5];
#pragma unroll
    for (int k = 0; k < 5; ++k) tk[k] = tap6(q, k);

    float bn = scale * (w6[5] - (float)mean) + be[c];
#pragma unroll
    for (int k = 0; k < 5; ++k) bn += tk[k] * (scale * w6[k]);
    float v = fast_elu(bn) * Wf[c];

#pragma unroll
    for (int off = 32; off; off >>= 1) v += __shfl_xor(v, off);
    if (lane == 0) red[w] = v;
    __syncthreads();
    if (c == 0) e_tab[bid] = red[0] + red[1] + red[2] + red[3] + bf;
}

// =============================================================================
// k_pre2: 480 blocks (pattern-per-block) x 256 threads (channel-per-thread).
// Redundant per-block yt-stats (identical op order -> bit-identical), then
// the proven register-dot pre-activation.
// =============================================================================
__global__ __launch_bounds__(256) void k_pre2(const uint* __restrict__ hist,
                                              const float* __restrict__ e_tab,
                                              const float* __restrict__ Wm,
                                              const float* __restrict__ gm,
                                              const float* __restrict__ bem,
                                              const float* __restrict__ Wo,
                                              const float* __restrict__ bo,
                                              float* __restrict__ spre0,
                                              float* __restrict__ spre1) {
    const int p = blockIdx.x;             // pattern 0..479
    const int c = threadIdx.x;            // channel / reduce index
    const int lane = c & 63, w = c >> 6;  // 4 waves
    __shared__ double wpart[4][2];
    __shared__ float syt[2];
    __shared__ float red[4][2];

    // ---- redundant yt mean/var over 480 bins (2 bins/thread) ----------------
    {
        double d1 = 0.0, d2 = 0.0;
        {
            const double n = (double)hist[(c >= 2 * NPAT) ? (c - NPAT) : (c % NPAT)];
            const double e = (double)e_tab[c];
            d1 = n * e; d2 = n * e * e;
        }
        if (c < 224) {
            const int b2 = c + 256;
            const double n = (double)hist[(b2 >= 2 * NPAT) ? (b2 - NPAT) : (b2 % NPAT)];
            const double e = (double)e_tab[b2];
            d1 += n * e; d2 += n * e * e;
        }
#pragma unroll
        for (int off = 32; off; off >>= 1) {
            d1 += __shfl_xor(d1, off);
            d2 += __shfl_xor(d2, off);
        }
        if (lane == 0) { wpart[w][0] = d1; wpart[w][1] = d2; }
        __syncthreads();
        if (c == 0) {
            const double a = wpart[0][0] + wpart[1][0] + wpart[2][0] + wpart[3][0];
            const double b2 = wpart[0][1] + wpart[1][1] + wpart[2][1] + wpart[3][1];
            const double mean = a / (3.0 * (double)CNT);
            const double var = b2 / (3.0 * (double)CNT) - mean * mean;
            syt[0] = (float)mean;
            syt[1] = (float)var;
        }
        __syncthreads();
    }

    // ---- pre-activation dot (proven register form) --------------------------
    const float du = e_tab[p] - syt[0];
    const float wm = Wm[c];
    const float A = gm[c] * wm * rsqrtf(wm * wm * syt[1] + EPS);
    const float mo = fast_elu(A * du + bem[c]);
    float a0 = mo * Wo[c * 2 + 0];
    float a1 = mo * Wo[c * 2 + 1];

#pragma unroll
    for (int off = 32; off; off >>= 1) {
        a0 += __shfl_xor(a0, off);
        a1 += __shfl_xor(a1, off);
    }
    if (lane == 0) { red[w][0] = a0; red[w][1] = a1; }
    __syncthreads();
    if (c == 0) {
        spre0[p] = red[0][0] + red[1][0] + red[2][0] + red[3][0] + bo[0];
        spre1[p] = red[0][1] + red[1][1] + red[2][1] + red[3][1] + bo[1];
    }
}

// =============================================================================
// k_wfin5: 256 blocks x 512 threads. Light finish (out-stats + table) +
// stream own row. Codes prefetched at kernel entry. [proven]
// =============================================================================
__global__ __launch_bounds__(512) void k_wfin5(const ushort_t* __restrict__ codes,
                                               const uint* __restrict__ hist,
                                               const float* __restrict__ spre0,
                                               const float* __restrict__ spre1,
                                               const float* __restrict__ go,
                                               const float* __restrict__ beo,
                                               float* __restrict__ out) {
    const int tid = threadIdx.x;
    const int lane = tid & 63, w = tid >> 6;   // 8 waves
    const int b = blockIdx.x;

    __shared__ float sp0[480], sp1[480], snn[480];
    __shared__ float2 tb[480];
    __shared__ double wpart[8][4];
    __shared__ double dstat[4];

    // prefetch this thread's codes early (use is after several barriers)
    const uint4 cw = *(const uint4*)(codes + (size_t)b * SEQL + tid * 8);

    if (tid < 480) {
        sp0[tid] = spre0[tid];
        sp1[tid] = spre1[tid];
        snn[tid] = (float)hist[(tid >= 2 * NPAT) ? (tid - NPAT) : (tid % NPAT)];
    }
    __syncthreads();

    // out-stats: 4 weighted f64 sums over 480 bins
    {
        double v4[4] = {0.0, 0.0, 0.0, 0.0};
        if (tid < 480) {
            const double n = (double)snn[tid];
            const double p0 = (double)sp0[tid], p1 = (double)sp1[tid];
            v4[0] = n * p0; v4[1] = n * p0 * p0; v4[2] = n * p1; v4[3] = n * p1 * p1;
        }
#pragma unroll
        for (int off = 32; off; off >>= 1)
#pragma unroll
            for (int s = 0; s < 4; ++s) v4[s] += __shfl_xor(v4[s], off);
        if (lane == 0)
#pragma unroll
            for (int s = 0; s < 4; ++s) wpart[w][s] = v4[s];
        __syncthreads();
        if (tid == 0) {
            double a[4] = {0.0, 0.0, 0.0, 0.0};
#pragma unroll
            for (int i = 0; i < 8; ++i)
#pragma unroll
                for (int s = 0; s < 4; ++s) a[s] += wpart[i][s];
#pragma unroll
            for (int s = 0; s < 4; ++s) dstat[s] = a[s];
        }
        __syncthreads();
    }

    // final output table (LDS)
    if (tid < 480) {
        const double m0 = dstat[0] / (3.0 * (double)CNT);
        const double v0 = dstat[1] / (3.0 * (double)CNT) - m0 * m0;
        const double m1 = dstat[2] / (3.0 * (double)CNT);
        const double v1 = dstat[3] / (3.0 * (double)CNT) - m1 * m1;
        const float sc0 = go[0] * rsqrtf((float)v0 + EPS);
        const float sc1 = go[1] * rsqrtf((float)v1 + EPS);
        tb[tid] = make_float2(sc0 * (sp0[tid] - (float)m0) + beo[0],
                              sc1 * (sp1[tid] - (float)m1) + beo[1]);
    }
    __syncthreads();

    // stream this block's row (8 positions/thread)
    const uint cw4[4] = {cw.x, cw.y, cw.z, cw.w};
    union { float f[48]; float4 v[12]; } u;
#pragma unroll
    for (int r = 0; r < 8; ++r) {
        const uint code = (cw4[r >> 1] >> ((r & 1) * 16)) & 0xffffu;
        const int qd = (int)(code & 0xffu), qp = (int)(code >> 8);
        const float2 v0 = tb[qd], v1 = tb[NPAT + qd], v2 = tb[2 * NPAT + qp];
        u.f[r * 6 + 0] = v0.x; u.f[r * 6 + 1] = v0.y;
        u.f[r * 6 + 2] = v1.x; u.f[r * 6 + 3] = v1.y;
        u.f[r * 6 + 4] = v2.x; u.f[r * 6 + 5] = v2.y;
    }
    float4* o = (float4*)(out + ((size_t)b * SEQL + (size_t)tid * 8) * 6);
#pragma unroll
    for (int r = 0; r < 12; ++r) o[r] = u.v[r];
}

// =============================================================================
extern "C" void kernel_launch(void* const* d_in, const int* in_sizes, int n_in,
                              void* d_out, int out_size, void* d_ws, size_t ws_size,
                              hipStream_t stream) {
    (void)in_sizes; (void)n_in; (void)out_size; (void)ws_size;
    const float* x = (const float*)d_in[0];
    const int* perms = (const int*)d_in[1];

    PtrPack pk;
    for (int j = 0; j < 3; ++j)
        for (int s = 0; s < 6; ++s)
            pk.p[6 * j + s] = (const float*)d_in[2 + 6 * j + s];

    const float* Wm  = (const float*)d_in[20];
    const float* gm  = (const float*)d_in[22];
    const float* bem = (const float*)d_in[23];
    const float* Wo  = (const float*)d_in[24];
    const float* bo  = (const float*)d_in[25];
    const float* go  = (const float*)d_in[26];
    const float* beo = (const float*)d_in[27];

    // ws layout: [0, 320K) u32 part[320][256]; [320K,321.25K) u32 hist[320];
    //            [321.5K..) f32 e_tab[480], spre0[480], spre1[480];
    //            [336K, 336K+2M) u16 codes
    uint*     part  = (uint*)d_ws;
    uint*     hist  = (uint*)((char*)d_ws + 327680);
    float*    e_tab = (float*)((char*)d_ws + 329216);
    float*    spre0 = (float*)((char*)d_ws + 331264);
    float*    spre1 = (float*)((char*)d_ws + 333312);
    ushort_t* codes = (ushort_t*)((char*)d_ws + 344064);

    k_prep<<<BATCH, 512, 0, stream>>>(x, perms, part, codes);
    k_hred<<<320, 64, 0, stream>>>(part, hist);
    k_etab3<<<480, 256, 0, stream>>>(pk, hist, e_tab);
    k_pre2<<<480, 256, 0, stream>>>(hist, e_tab, Wm, gm, bem, Wo, bo, spre0, spre1);
    k_wfin5<<<BATCH, 512, 0, stream>>>(codes, hist, spre0, spre1, go, beo,
                                       (float*)d_out);
}

// Round 17
// 36.038 us; speedup vs baseline: 1.7840x; 1.0545x over previous
//
#include <hip/hip_runtime.h>
#include <hip/hip_bf16.h>
#include <math.h>

#define BATCH 256
#define SEQL  4096
#define DIMC  256
#define NPAT  160
#define CNT   (BATCH * SEQL)     // per-stream element count (over B,L)
#define EPS   1e-3f

typedef unsigned int uint;
typedef unsigned short ushort_t;
typedef unsigned char uchar;

// ---------------- shared helpers ----------------------------------------------
__device__ __forceinline__ int pad_mask(int type) {
    return (type == 0) ? 0 : (type == 1) ? 3 : (type == 2) ? 1 : (type == 3) ? 16 : 24;
}

// tap value for extended-pattern q, index k in [0,6): k==5 is the constant 1.
__device__ __forceinline__ float tap6(int q, int k) {
    if (k == 5) return 1.0f;
    const int type = q >> 5, bits = q & 31;
    const int pm = pad_mask(type);
    if ((pm >> k) & 1) return 0.0f;
    return ((bits >> k) & 1) ? 1.0f : -1.0f;
}

__device__ __forceinline__ float fast_elu(float x) {
    return x > 0.0f ? x : (__expf(x) - 1.0f);
}

__device__ __forceinline__ int pat_type(int t) {
    if (t >= 2 && t < SEQL - 2) return 0;
    if (t == 0) return 1;
    if (t == 1) return 2;
    if (t == SEQL - 2) return 3;
    return 4;
}

struct PtrPack { const float* p[18]; };  // per stream: Wc, bc, g, be, Wf, bf

// =============================================================================
// k_prep: vectorized bit-pack (byte-per-thread, no ballots), per-position
// codes, per-wave sub-histograms -> per-block partials. 256 blocks x 512 thr.
// =============================================================================
__global__ __launch_bounds__(512) void k_prep(const float* __restrict__ x,
                                              const int* __restrict__ perms,
                                              uint* __restrict__ part,
                                              ushort_t* __restrict__ codes) {
    __shared__ uint xw[130];        // word 0 and 129 are zero sentinels
    __shared__ uint xwI[130];
    __shared__ uint h8[8][320];     // per-wave histograms
    const int b = blockIdx.x, tid = threadIdx.x;
    const int w = tid >> 6;

    for (int i = tid; i < 8 * 320; i += 512) ((uint*)h8)[i] = 0;
    if (tid < 2) { xw[tid * 129] = 0; xwI[tid * 129] = 0; }

    const float* xr = x + (size_t)b * SEQL;
    const int* pr = perms + (size_t)b * SEQL;

    // direct bits: thread tid -> elements [tid*8, tid*8+8), one byte
    {
        const float4 f0 = ((const float4*)xr)[tid * 2];
        const float4 f1 = ((const float4*)xr)[tid * 2 + 1];
        uint byte = 0;
        byte |= (f0.x > 0.5f) ? 1u : 0u;
        byte |= (f0.y > 0.5f) ? 2u : 0u;
        byte |= (f0.z > 0.5f) ? 4u : 0u;
        byte |= (f0.w > 0.5f) ? 8u : 0u;
        byte |= (f1.x > 0.5f) ? 16u : 0u;
        byte |= (f1.y > 0.5f) ? 32u : 0u;
        byte |= (f1.z > 0.5f) ? 64u : 0u;
        byte |= (f1.w > 0.5f) ? 128u : 0u;
        ((uchar*)(xw + 1))[tid] = (uchar)byte;
    }
    __syncthreads();

    // interleaved bits: gather via packed direct words
    {
        const int4 p0 = ((const int4*)pr)[tid * 2];
        const int4 p1 = ((const int4*)pr)[tid * 2 + 1];
        uint byte = 0;
        byte |= ((xw[1 + (p0.x >> 5)] >> (p0.x & 31)) & 1u);
        byte |= ((xw[1 + (p0.y >> 5)] >> (p0.y & 31)) & 1u) << 1;
        byte |= ((xw[1 + (p0.z >> 5)] >> (p0.z & 31)) & 1u) << 2;
        byte |= ((xw[1 + (p0.w >> 5)] >> (p0.w & 31)) & 1u) << 3;
        byte |= ((xwI[0] = 0, (xw[1 + (p1.x >> 5)] >> (p1.x & 31)) & 1u)) << 4;
        byte |= ((xw[1 + (p1.y >> 5)] >> (p1.y & 31)) & 1u) << 5;
        byte |= ((xw[1 + (p1.z >> 5)] >> (p1.z & 31)) & 1u) << 6;
        byte |= ((xw[1 + (p1.w >> 5)] >> (p1.w & 31)) & 1u) << 7;
        ((uchar*)(xwI + 1))[tid] = (uchar)byte;
    }
    __syncthreads();

    // codes + per-wave hist (8 consecutive positions per thread)
    const int t0 = tid * 8;
    const int wd = (t0 + 30) >> 5;
    const int sh0 = (t0 + 30) & 31;
    const unsigned long long Wd = (unsigned long long)xw[wd] | ((unsigned long long)xw[wd + 1] << 32);
    const unsigned long long Wi = (unsigned long long)xwI[wd] | ((unsigned long long)xwI[wd + 1] << 32);
    int c[8];
#pragma unroll
    for (int r = 0; r < 8; ++r) {
        const int t = t0 + r;
        const int type = pat_type(t);
        const int qd = type * 32 + (int)((Wd >> (sh0 + r)) & 31ull);
        const int qp = type * 32 + (int)((Wi >> (sh0 + r)) & 31ull);
        atomicAdd(&h8[w][qd], 1u);
        atomicAdd(&h8[w][NPAT + qp], 1u);
        c[r] = qd | (qp << 8);
    }
    uint4 cv;
    cv.x = (uint)(c[0] | (c[1] << 16));
    cv.y = (uint)(c[2] | (c[3] << 16));
    cv.z = (uint)(c[4] | (c[5] << 16));
    cv.w = (uint)(c[6] | (c[7] << 16));
    *(uint4*)(codes + (size_t)b * SEQL + t0) = cv;
    __syncthreads();

    // reduce per-wave hists -> per-block partials (transposed for k_hred)
    if (tid < 2 * NPAT) {
        uint s = 0;
#pragma unroll
        for (int i = 0; i < 8; ++i) s += h8[i][tid];
        part[(size_t)tid * 256 + b] = s;
    }
}

// =============================================================================
// k_hred: 320 blocks x 64 threads — bin-per-block reduce of the partials. [proven]
// =============================================================================
__global__ __launch_bounds__(64) void k_hred(const uint* __restrict__ part,
                                             uint* __restrict__ hist) {
    const int bin = blockIdx.x, lane = threadIdx.x;
    const uint4 v = *(const uint4*)(part + (size_t)bin * 256 + lane * 4);
    uint s = v.x + v.y + v.z + v.w;
#pragma unroll
    for (int off = 32; off; off >>= 1) s += __shfl_xor(s, off);
    if (lane == 0) hist[bin] = s;
}

// =============================================================================
// k_etab3: e-table, 480 blocks (one per (stream j, pattern q)) x 256 threads.
// [proven]
// =============================================================================
__global__ __launch_bounds__(256) void k_etab3(PtrPack pk,
                                               const uint* __restrict__ hist,
                                               float* __restrict__ e_tab) {
    const int bid = blockIdx.x;           // 0..479
    const int j = bid / NPAT, q = bid % NPAT;
    const int c = threadIdx.x;            // channel
    const int lane = c & 63, w = c >> 6;  // 4 waves

    __shared__ float sh[NPAT];
    __shared__ float m6p[21][8];
    __shared__ float sM6[21];
    __shared__ float red[4];

    if (c < NPAT) sh[c] = (float)hist[(j == 2 ? NPAT : 0) + c];
    __syncthreads();

    if (c < 168) {
        const int e = c >> 3, prt = c & 7;
        int k = 0, rem = e;
        while (rem > 5 - k) { rem -= 6 - k; ++k; }
        const int l = k + rem;
        float S = 0.0f;
        for (int qq = prt * 20; qq < prt * 20 + 20; ++qq)
            S += sh[qq] * tap6(qq, k) * tap6(qq, l);
        m6p[e][prt] = S;
    }
    __syncthreads();
    if (c < 21) {
        float S = 0.0f;
#pragma unroll
        for (int p = 0; p < 8; ++p) S += m6p[c][p];
        sM6[c] = S;
    }
    __syncthreads();

    const float* Wc = pk.p[6 * j + 0];
    const float* bc = pk.p[6 * j + 1];
    const float* g  = pk.p[6 * j + 2];
    const float* be = pk.p[6 * j + 3];
    const float* Wf = pk.p[6 * j + 4];
    const float  bf = pk.p[6 * j + 5][0];

    float w6[6];
#pragma unroll
    for (int k = 0; k < 5; ++k) w6[k] = Wc[k * DIMC + c];
    w6[5] = bc[c];

    double Ey = 0.0, Ey2 = 0.0;
    {
        int e = 0;
#pragma unroll
        for (int k = 0; k < 6; ++k) {
#pragma unroll
            for (int l = k; l < 6; ++l, ++e) {
                const double p = (double)w6[k] * (double)w6[l] * (double)sM6[e];
                Ey2 += (l == k) ? p : 2.0 * p;
                if (l == 5) Ey += (double)w6[k] * (double)sM6[e];
            }
        }
    }
    const double mean = Ey / (double)CNT;
    const double var = Ey2 / (double)CNT - mean * mean;
    const float scale = g[c] * rsqrtf((float)var + EPS);

    float tk[5];
#pragma unroll
    for (int k = 0; k < 5; ++k) tk[k] = tap6(q, k);

    float bn = scale * (w6[5] - (float)mean) + be[c];
#pragma unroll
    for (int k = 0; k < 5; ++k) bn += tk[k] * (scale * w6[k]);
    float v = fast_elu(bn) * Wf[c];

#pragma unroll
    for (int off = 32; off; off >>= 1) v += __shfl_xor(v, off);
    if (lane == 0) red[w] = v;
    __syncthreads();
    if (c == 0) e_tab[bid] = red[0] + red[1] + red[2] + red[3] + bf;
}

// =============================================================================
// k_pre2: 480 blocks (pattern-per-block) x 256 threads. Redundant per-block
// yt-stats + register-dot pre-activation. [proven]
// =============================================================================
__global__ __launch_bounds__(256) void k_pre2(const uint* __restrict__ hist,
                                              const float* __restrict__ e_tab,
                                              const float* __restrict__ Wm,
                                              const float* __restrict__ gm,
                                              const float* __restrict__ bem,
                                              const float* __restrict__ Wo,
                                              const float* __restrict__ bo,
                                              float* __restrict__ spre0,
                                              float* __restrict__ spre1) {
    const int p = blockIdx.x;             // pattern 0..479
    const int c = threadIdx.x;            // channel / reduce index
    const int lane = c & 63, w = c >> 6;  // 4 waves
    __shared__ double wpart[4][2];
    __shared__ float syt[2];
    __shared__ float red[4][2];

    {
        double d1 = 0.0, d2 = 0.0;
        {
            const double n = (double)hist[(c >= 2 * NPAT) ? (c - NPAT) : (c % NPAT)];
            const double e = (double)e_tab[c];
            d1 = n * e; d2 = n * e * e;
        }
        if (c < 224) {
            const int b2 = c + 256;
            const double n = (double)hist[(b2 >= 2 * NPAT) ? (b2 - NPAT) : (b2 % NPAT)];
            const double e = (double)e_tab[b2];
            d1 += n * e; d2 += n * e * e;
        }
#pragma unroll
        for (int off = 32; off; off >>= 1) {
            d1 += __shfl_xor(d1, off);
            d2 += __shfl_xor(d2, off);
        }
        if (lane == 0) { wpart[w][0] = d1; wpart[w][1] = d2; }
        __syncthreads();
        if (c == 0) {
            const double a = wpart[0][0] + wpart[1][0] + wpart[2][0] + wpart[3][0];
            const double b2 = wpart[0][1] + wpart[1][1] + wpart[2][1] + wpart[3][1];
            const double mean = a / (3.0 * (double)CNT);
            const double var = b2 / (3.0 * (double)CNT) - mean * mean;
            syt[0] = (float)mean;
            syt[1] = (float)var;
        }
        __syncthreads();
    }

    const float du = e_tab[p] - syt[0];
    const float wm = Wm[c];
    const float A = gm[c] * wm * rsqrtf(wm * wm * syt[1] + EPS);
    const float mo = fast_elu(A * du + bem[c]);
    float a0 = mo * Wo[c * 2 + 0];
    float a1 = mo * Wo[c * 2 + 1];

#pragma unroll
    for (int off = 32; off; off >>= 1) {
        a0 += __shfl_xor(a0, off);
        a1 += __shfl_xor(a1, off);
    }
    if (lane == 0) { red[w][0] = a0; red[w][1] = a1; }
    __syncthreads();
    if (c == 0) {
        spre0[p] = red[0][0] + red[1][0] + red[2][0] + red[3][0] + bo[0];
        spre1[p] = red[0][1] + red[1][1] + red[2][1] + red[3][1] + bo[1];
    }
}

// =============================================================================
// k_wfin5: 256 blocks x 512 threads. Light finish + stream own row. [proven]
// =============================================================================
__global__ __launch_bounds__(512) void k_wfin5(const ushort_t* __restrict__ codes,
                                               const uint* __restrict__ hist,
                                               const float* __restrict__ spre0,
                                               const float* __restrict__ spre1,
                                               const float* __restrict__ go,
                                               const float* __restrict__ beo,
                                               float* __restrict__ out) {
    const int tid = threadIdx.x;
    const int lane = tid & 63, w = tid >> 6;   // 8 waves
    const int b = blockIdx.x;

    __shared__ float sp0[480], sp1[480], snn[480];
    __shared__ float2 tb[480];
    __shared__ double wpart[8][4];
    __shared__ double dstat[4];

    const uint4 cw = *(const uint4*)(codes + (size_t)b * SEQL + tid * 8);

    if (tid < 480) {
        sp0[tid] = spre0[tid];
        sp1[tid] = spre1[tid];
        snn[tid] = (float)hist[(tid >= 2 * NPAT) ? (tid - NPAT) : (tid % NPAT)];
    }
    __syncthreads();

    {
        double v4[4] = {0.0, 0.0, 0.0, 0.0};
        if (tid < 480) {
            const double n = (double)snn[tid];
            const double p0 = (double)sp0[tid], p1 = (double)sp1[tid];
            v4[0] = n * p0; v4[1] = n * p0 * p0; v4[2] = n * p1; v4[3] = n * p1 * p1;
        }
#pragma unroll
        for (int off = 32; off; off >>= 1)
#pragma unroll
            for (int s = 0; s < 4; ++s) v4[s] += __shfl_xor(v4[s], off);
        if (lane == 0)
#pragma unroll
            for (int s = 0; s < 4; ++s) wpart[w][s] = v4[s];
        __syncthreads();
        if (tid == 0) {
            double a[4] = {0.0, 0.0, 0.0, 0.0};
#pragma unroll
            for (int i = 0; i < 8; ++i)
#pragma unroll
                for (int s = 0; s < 4; ++s) a[s] += wpart[i][s];
#pragma unroll
            for (int s = 0; s < 4; ++s) dstat[s] = a[s];
        }
        __syncthreads();
    }

    if (tid < 480) {
        const double m0 = dstat[0] / (3.0 * (double)CNT);
        const double v0 = dstat[1] / (3.0 * (double)CNT) - m0 * m0;
        const double m1 = dstat[2] / (3.0 * (double)CNT);
        const double v1 = dstat[3] / (3.0 * (double)CNT) - m1 * m1;
        const float sc0 = go[0] * rsqrtf((float)v0 + EPS);
        const float sc1 = go[1] * rsqrtf((float)v1 + EPS);
        tb[tid] = make_float2(sc0 * (sp0[tid] - (float)m0) + beo[0],
                              sc1 * (sp1[tid] - (float)m1) + beo[1]);
    }
    __syncthreads();

    const uint cw4[4] = {cw.x, cw.y, cw.z, cw.w};
    union { float f[48]; float4 v[12]; } u;
#pragma unroll
    for (int r = 0; r < 8; ++r) {
        const uint code = (cw4[r >> 1] >> ((r & 1) * 16)) & 0xffffu;
        const int qd = (int)(code & 0xffu), qp = (int)(code >> 8);
        const float2 v0 = tb[qd], v1 = tb[NPAT + qd], v2 = tb[2 * NPAT + qp];
        u.f[r * 6 + 0] = v0.x; u.f[r * 6 + 1] = v0.y;
        u.f[r * 6 + 2] = v1.x; u.f[r * 6 + 3] = v1.y;
        u.f[r * 6 + 4] = v2.x; u.f[r * 6 + 5] = v2.y;
    }
    float4* o = (float4*)(out + ((size_t)b * SEQL + (size_t)tid * 8) * 6);
#pragma unroll
    for (int r = 0; r < 12; ++r) o[r] = u.v[r];
}

// =============================================================================
extern "C" void kernel_launch(void* const* d_in, const int* in_sizes, int n_in,
                              void* d_out, int out_size, void* d_ws, size_t ws_size,
                              hipStream_t stream) {
    (void)in_sizes; (void)n_in; (void)out_size; (void)ws_size;
    const float* x = (const float*)d_in[0];
    const int* perms = (const int*)d_in[1];

    PtrPack pk;
    for (int j = 0; j < 3; ++j)
        for (int s = 0; s < 6; ++s)
            pk.p[6 * j + s] = (const float*)d_in[2 + 6 * j + s];

    const float* Wm  = (const float*)d_in[20];
    const float* gm  = (const float*)d_in[22];
    const float* bem = (const float*)d_in[23];
    const float* Wo  = (const float*)d_in[24];
    const float* bo  = (const float*)d_in[25];
    const float* go  = (const float*)d_in[26];
    const float* beo = (const float*)d_in[27];

    // ws layout: [0, 320K) u32 part[320][256]; [320K,321.25K) u32 hist[320];
    //            [321.5K..) f32 e_tab[480], spre0[480], spre1[480];
    //            [336K, 336K+2M) u16 codes
    uint*     part  = (uint*)d_ws;
    uint*     hist  = (uint*)((char*)d_ws + 327680);
    float*    e_tab = (float*)((char*)d_ws + 329216);
    float*    spre0 = (float*)((char*)d_ws + 331264);
    float*    spre1 = (float*)((char*)d_ws + 333312);
    ushort_t* codes = (ushort_t*)((char*)d_ws + 344064);

    k_prep<<<BATCH, 512, 0, stream>>>(x, perms, part, codes);
    k_hred<<<320, 64, 0, stream>>>(part, hist);
    k_etab3<<<480, 256, 0, stream>>>(pk, hist, e_tab);
    k_pre2<<<480, 256, 0, stream>>>(hist, e_tab, Wm, gm, bem, Wo, bo, spre0, spre1);
    k_wfin5<<<BATCH, 512, 0, stream>>>(codes, hist, spre0, spre1, go, beo,
                                       (float*)d_out);
}

// Round 18
// 36.031 us; speedup vs baseline: 1.7844x; 1.0002x over previous
//
#include <hip/hip_runtime.h>
#include <hip/hip_bf16.h>
#include <math.h>

#define BATCH 256
#define SEQL  4096
#define DIMC  256
#define NPAT  160
#define CNT   (BATCH * SEQL)     // per-stream element count (over B,L)
#define EPS   1e-3f

typedef unsigned int uint;
typedef unsigned char uchar;

// ---------------- shared helpers ----------------------------------------------
__device__ __forceinline__ int pad_mask(int type) {
    return (type == 0) ? 0 : (type == 1) ? 3 : (type == 2) ? 1 : (type == 3) ? 16 : 24;
}

// tap value for extended-pattern q, index k in [0,6): k==5 is the constant 1.
__device__ __forceinline__ float tap6(int q, int k) {
    if (k == 5) return 1.0f;
    const int type = q >> 5, bits = q & 31;
    const int pm = pad_mask(type);
    if ((pm >> k) & 1) return 0.0f;
    return ((bits >> k) & 1) ? 1.0f : -1.0f;
}

__device__ __forceinline__ float fast_elu(float x) {
    return x > 0.0f ? x : (__expf(x) - 1.0f);
}

__device__ __forceinline__ int pat_type(int t) {
    if (t >= 2 && t < SEQL - 2) return 0;
    if (t == 0) return 1;
    if (t == 1) return 2;
    if (t == SEQL - 2) return 3;
    return 4;
}

struct PtrPack { const float* p[18]; };  // per stream: Wc, bc, g, be, Wf, bf

// =============================================================================
// k_prep: vectorized bit-pack (byte-per-thread, no ballots), per-wave
// sub-histograms -> per-block partials, packed bit rows -> global (1 KB/row).
// 256 blocks x 512 threads.
// =============================================================================
__global__ __launch_bounds__(512) void k_prep(const float* __restrict__ x,
                                              const int* __restrict__ perms,
                                              uint* __restrict__ part,
                                              uint* __restrict__ pkbits) {
    __shared__ uint xw[130];        // word 0 and 129 are zero sentinels
    __shared__ uint xwI[130];
    __shared__ uint h8[8][320];     // per-wave histograms
    const int b = blockIdx.x, tid = threadIdx.x;
    const int w = tid >> 6;

    for (int i = tid; i < 8 * 320; i += 512) ((uint*)h8)[i] = 0;
    if (tid < 2) { xw[tid * 129] = 0; xwI[tid * 129] = 0; }

    const float* xr = x + (size_t)b * SEQL;
    const int* pr = perms + (size_t)b * SEQL;

    // direct bits: thread tid -> elements [tid*8, tid*8+8), one byte
    {
        const float4 f0 = ((const float4*)xr)[tid * 2];
        const float4 f1 = ((const float4*)xr)[tid * 2 + 1];
        uint byte = 0;
        byte |= (f0.x > 0.5f) ? 1u : 0u;
        byte |= (f0.y > 0.5f) ? 2u : 0u;
        byte |= (f0.z > 0.5f) ? 4u : 0u;
        byte |= (f0.w > 0.5f) ? 8u : 0u;
        byte |= (f1.x > 0.5f) ? 16u : 0u;
        byte |= (f1.y > 0.5f) ? 32u : 0u;
        byte |= (f1.z > 0.5f) ? 64u : 0u;
        byte |= (f1.w > 0.5f) ? 128u : 0u;
        ((uchar*)(xw + 1))[tid] = (uchar)byte;
    }
    __syncthreads();

    // interleaved bits: gather via packed direct words
    {
        const int4 p0 = ((const int4*)pr)[tid * 2];
        const int4 p1 = ((const int4*)pr)[tid * 2 + 1];
        uint byte = 0;
        byte |= ((xw[1 + (p0.x >> 5)] >> (p0.x & 31)) & 1u);
        byte |= ((xw[1 + (p0.y >> 5)] >> (p0.y & 31)) & 1u) << 1;
        byte |= ((xw[1 + (p0.z >> 5)] >> (p0.z & 31)) & 1u) << 2;
        byte |= ((xw[1 + (p0.w >> 5)] >> (p0.w & 31)) & 1u) << 3;
        byte |= ((xw[1 + (p1.x >> 5)] >> (p1.x & 31)) & 1u) << 4;
        byte |= ((xw[1 + (p1.y >> 5)] >> (p1.y & 31)) & 1u) << 5;
        byte |= ((xw[1 + (p1.z >> 5)] >> (p1.z & 31)) & 1u) << 6;
        byte |= ((xw[1 + (p1.w >> 5)] >> (p1.w & 31)) & 1u) << 7;
        ((uchar*)(xwI + 1))[tid] = (uchar)byte;
    }
    __syncthreads();

    // export packed rows (128 direct + 128 interleaved words = 1 KB/row)
    if (tid < 128) pkbits[(size_t)b * 256 + tid] = xw[1 + tid];
    else if (tid < 256) pkbits[(size_t)b * 256 + tid] = xwI[tid - 127];

    // per-wave hist (8 consecutive positions per thread)
    const int t0 = tid * 8;
    const int wd = (t0 + 30) >> 5;
    const int sh0 = (t0 + 30) & 31;
    const unsigned long long Wd = (unsigned long long)xw[wd] | ((unsigned long long)xw[wd + 1] << 32);
    const unsigned long long Wi = (unsigned long long)xwI[wd] | ((unsigned long long)xwI[wd + 1] << 32);
#pragma unroll
    for (int r = 0; r < 8; ++r) {
        const int t = t0 + r;
        const int type = pat_type(t);
        const int qd = type * 32 + (int)((Wd >> (sh0 + r)) & 31ull);
        const int qp = type * 32 + (int)((Wi >> (sh0 + r)) & 31ull);
        atomicAdd(&h8[w][qd], 1u);
        atomicAdd(&h8[w][NPAT + qp], 1u);
    }
    __syncthreads();

    // reduce per-wave hists -> per-block partials (transposed for k_hred)
    if (tid < 2 * NPAT) {
        uint s = 0;
#pragma unroll
        for (int i = 0; i < 8; ++i) s += h8[i][tid];
        part[(size_t)tid * 256 + b] = s;
    }
}

// =============================================================================
// k_hred: 320 blocks x 64 threads — bin-per-block reduce of the partials. [proven]
// =============================================================================
__global__ __launch_bounds__(64) void k_hred(const uint* __restrict__ part,
                                             uint* __restrict__ hist) {
    const int bin = blockIdx.x, lane = threadIdx.x;
    const uint4 v = *(const uint4*)(part + (size_t)bin * 256 + lane * 4);
    uint s = v.x + v.y + v.z + v.w;
#pragma unroll
    for (int off = 32; off; off >>= 1) s += __shfl_xor(s, off);
    if (lane == 0) hist[bin] = s;
}

// =============================================================================
// k_etab3: e-table, 480 blocks (one per (stream j, pattern q)) x 256 threads.
// [proven]
// =============================================================================
__global__ __launch_bounds__(256) void k_etab3(PtrPack pk,
                                               const uint* __restrict__ hist,
                                               float* __restrict__ e_tab) {
    const int bid = blockIdx.x;           // 0..479
    const int j = bid / NPAT, q = bid % NPAT;
    const int c = threadIdx.x;            // channel
    const int lane = c & 63, w = c >> 6;  // 4 waves

    __shared__ float sh[NPAT];
    __shared__ float m6p[21][8];
    __shared__ float sM6[21];
    __shared__ float red[4];

    if (c < NPAT) sh[c] = (float)hist[(j == 2 ? NPAT : 0) + c];
    __syncthreads();

    if (c < 168) {
        const int e = c >> 3, prt = c & 7;
        int k = 0, rem = e;
        while (rem > 5 - k) { rem -= 6 - k; ++k; }
        const int l = k + rem;
        float S = 0.0f;
        for (int qq = prt * 20; qq < prt * 20 + 20; ++qq)
            S += sh[qq] * tap6(qq, k) * tap6(qq, l);
        m6p[e][prt] = S;
    }
    __syncthreads();
    if (c < 21) {
        float S = 0.0f;
#pragma unroll
        for (int p = 0; p < 8; ++p) S += m6p[c][p];
        sM6[c] = S;
    }
    __syncthreads();

    const float* Wc = pk.p[6 * j + 0];
    const float* bc = pk.p[6 * j + 1];
    const float* g  = pk.p[6 * j + 2];
    const float* be = pk.p[6 * j + 3];
    const float* Wf = pk.p[6 * j + 4];
    const float  bf = pk.p[6 * j + 5][0];

    float w6[6];
#pragma unroll
    for (int k = 0; k < 5; ++k) w6[k] = Wc[k * DIMC + c];
    w6[5] = bc[c];

    double Ey = 0.0, Ey2 = 0.0;
    {
        int e = 0;
#pragma unroll
        for (int k = 0; k < 6; ++k) {
#pragma unroll
            for (int l = k; l < 6; ++l, ++e) {
                const double p = (double)w6[k] * (double)w6[l] * (double)sM6[e];
                Ey2 += (l == k) ? p : 2.0 * p;
                if (l == 5) Ey += (double)w6[k] * (double)sM6[e];
            }
        }
    }
    const double mean = Ey / (double)CNT;
    const double var = Ey2 / (double)CNT - mean * mean;
    const float scale = g[c] * rsqrtf((float)var + EPS);

    float tk[5];
#pragma unroll
    for (int k = 0; k < 5; ++k) tk[k] = tap6(q, k);

    float bn = scale * (w6[5] - (float)mean) + be[c];
#pragma unroll
    for (int k = 0; k < 5; ++k) bn += tk[k] * (scale * w6[k]);
    float v = fast_elu(bn) * Wf[c];

#pragma unroll
    for (int off = 32; off; off >>= 1) v += __shfl_xor(v, off);
    if (lane == 0) red[w] = v;
    __syncthreads();
    if (c == 0) e_tab[bid] = red[0] + red[1] + red[2] + red[3] + bf;
}

// =============================================================================
// k_pre2: 480 blocks (pattern-per-block) x 256 threads. Redundant per-block
// yt-stats + register-dot pre-activation. [proven]
// =============================================================================
__global__ __launch_bounds__(256) void k_pre2(const uint* __restrict__ hist,
                                              const float* __restrict__ e_tab,
                                              const float* __restrict__ Wm,
                                              const float* __restrict__ gm,
                                              const float* __restrict__ bem,
                                              const float* __restrict__ Wo,
                                              const float* __restrict__ bo,
                                              float* __restrict__ spre0,
                                              float* __restrict__ spre1) {
    const int p = blockIdx.x;             // pattern 0..479
    const int c = threadIdx.x;            // channel / reduce index
    const int lane = c & 63, w = c >> 6;  // 4 waves
    __shared__ double wpart[4][2];
    __shared__ float syt[2];
    __shared__ float red[4][2];

    {
        double d1 = 0.0, d2 = 0.0;
        {
            const double n = (double)hist[(c >= 2 * NPAT) ? (c - NPAT) : (c % NPAT)];
            const double e = (double)e_tab[c];
            d1 = n * e; d2 = n * e * e;
        }
        if (c < 224) {
            const int b2 = c + 256;
            const double n = (double)hist[(b2 >= 2 * NPAT) ? (b2 - NPAT) : (b2 % NPAT)];
            const double e = (double)e_tab[b2];
            d1 += n * e; d2 += n * e * e;
        }
#pragma unroll
        for (int off = 32; off; off >>= 1) {
            d1 += __shfl_xor(d1, off);
            d2 += __shfl_xor(d2, off);
        }
        if (lane == 0) { wpart[w][0] = d1; wpart[w][1] = d2; }
        __syncthreads();
        if (c == 0) {
            const double a = wpart[0][0] + wpart[1][0] + wpart[2][0] + wpart[3][0];
            const double b2 = wpart[0][1] + wpart[1][1] + wpart[2][1] + wpart[3][1];
            const double mean = a / (3.0 * (double)CNT);
            const double var = b2 / (3.0 * (double)CNT) - mean * mean;
            syt[0] = (float)mean;
            syt[1] = (float)var;
        }
        __syncthreads();
    }

    const float du = e_tab[p] - syt[0];
    const float wm = Wm[c];
    const float A = gm[c] * wm * rsqrtf(wm * wm * syt[1] + EPS);
    const float mo = fast_elu(A * du + bem[c]);
    float a0 = mo * Wo[c * 2 + 0];
    float a1 = mo * Wo[c * 2 + 1];

#pragma unroll
    for (int off = 32; off; off >>= 1) {
        a0 += __shfl_xor(a0, off);
        a1 += __shfl_xor(a1, off);
    }
    if (lane == 0) { red[w][0] = a0; red[w][1] = a1; }
    __syncthreads();
    if (c == 0) {
        spre0[p] = red[0][0] + red[1][0] + red[2][0] + red[3][0] + bo[0];
        spre1[p] = red[0][1] + red[1][1] + red[2][1] + red[3][1] + bo[1];
    }
}

// =============================================================================
// k_wfin6: 256 blocks x 512 threads. Light finish (out-stats + table) +
// inline pattern decode from packed bits (1 KB/row) + stream own row.
// =============================================================================
__global__ __launch_bounds__(512) void k_wfin6(const uint* __restrict__ pkbits,
                                               const uint* __restrict__ hist,
                                               const float* __restrict__ spre0,
                                               const float* __restrict__ spre1,
                                               const float* __restrict__ go,
                                               const float* __restrict__ beo,
                                               float* __restrict__ out) {
    const int tid = threadIdx.x;
    const int lane = tid & 63, w = tid >> 6;   // 8 waves
    const int b = blockIdx.x;

    __shared__ uint bw[130], bwI[130];         // packed rows, zero sentinels
    __shared__ float sp0[480], sp1[480], snn[480];
    __shared__ float2 tb[480];
    __shared__ double wpart[8][4];
    __shared__ double dstat[4];

    // load this row's packed bits early (covered by the first barrier)
    if (tid < 128) bw[1 + tid] = pkbits[(size_t)b * 256 + tid];
    else if (tid < 256) bwI[tid - 127] = pkbits[(size_t)b * 256 + tid];
    if (tid < 2) { bw[tid * 129] = 0; bwI[tid * 129] = 0; }

    if (tid < 480) {
        sp0[tid] = spre0[tid];
        sp1[tid] = spre1[tid];
        snn[tid] = (float)hist[(tid >= 2 * NPAT) ? (tid - NPAT) : (tid % NPAT)];
    }
    __syncthreads();

    // out-stats: 4 weighted f64 sums over 480 bins
    {
        double v4[4] = {0.0, 0.0, 0.0, 0.0};
        if (tid < 480) {
            const double n = (double)snn[tid];
            const double p0 = (double)sp0[tid], p1 = (double)sp1[tid];
            v4[0] = n * p0; v4[1] = n * p0 * p0; v4[2] = n * p1; v4[3] = n * p1 * p1;
        }
#pragma unroll
        for (int off = 32; off; off >>= 1)
#pragma unroll
            for (int s = 0; s < 4; ++s) v4[s] += __shfl_xor(v4[s], off);
        if (lane == 0)
#pragma unroll
            for (int s = 0; s < 4; ++s) wpart[w][s] = v4[s];
        __syncthreads();
        if (tid == 0) {
            double a[4] = {0.0, 0.0, 0.0, 0.0};
#pragma unroll
            for (int i = 0; i < 8; ++i)
#pragma unroll
                for (int s = 0; s < 4; ++s) a[s] += wpart[i][s];
#pragma unroll
            for (int s = 0; s < 4; ++s) dstat[s] = a[s];
        }
        __syncthreads();
    }

    // final output table (LDS)
    if (tid < 480) {
        const double m0 = dstat[0] / (3.0 * (double)CNT);
        const double v0 = dstat[1] / (3.0 * (double)CNT) - m0 * m0;
        const double m1 = dstat[2] / (3.0 * (double)CNT);
        const double v1 = dstat[3] / (3.0 * (double)CNT) - m1 * m1;
        const float sc0 = go[0] * rsqrtf((float)v0 + EPS);
        const float sc1 = go[1] * rsqrtf((float)v1 + EPS);
        tb[tid] = make_float2(sc0 * (sp0[tid] - (float)m0) + beo[0],
                              sc1 * (sp1[tid] - (float)m1) + beo[1]);
    }
    __syncthreads();

    // decode patterns inline + stream this block's row (8 positions/thread)
    const int t0 = tid * 8;
    const int wd = (t0 + 30) >> 5;
    const int sh0 = (t0 + 30) & 31;
    const unsigned long long Wd = (unsigned long long)bw[wd] | ((unsigned long long)bw[wd + 1] << 32);
    const unsigned long long Wi = (unsigned long long)bwI[wd] | ((unsigned long long)bwI[wd + 1] << 32);
    union { float f[48]; float4 v[12]; } u;
#pragma unroll
    for (int r = 0; r < 8; ++r) {
        const int t = t0 + r;
        const int type = pat_type(t);
        const int qd = type * 32 + (int)((Wd >> (sh0 + r)) & 31ull);
        const int qp = type * 32 + (int)((Wi >> (sh0 + r)) & 31ull);
        const float2 v0 = tb[qd], v1 = tb[NPAT + qd], v2 = tb[2 * NPAT + qp];
        u.f[r * 6 + 0] = v0.x; u.f[r * 6 + 1] = v0.y;
        u.f[r * 6 + 2] = v1.x; u.f[r * 6 + 3] = v1.y;
        u.f[r * 6 + 4] = v2.x; u.f[r * 6 + 5] = v2.y;
    }
    float4* o = (float4*)(out + ((size_t)b * SEQL + (size_t)t0) * 6);
#pragma unroll
    for (int r = 0; r < 12; ++r) o[r] = u.v[r];
}

// =============================================================================
extern "C" void kernel_launch(void* const* d_in, const int* in_sizes, int n_in,
                              void* d_out, int out_size, void* d_ws, size_t ws_size,
                              hipStream_t stream) {
    (void)in_sizes; (void)n_in; (void)out_size; (void)ws_size;
    const float* x = (const float*)d_in[0];
    const int* perms = (const int*)d_in[1];

    PtrPack pk;
    for (int j = 0; j < 3; ++j)
        for (int s = 0; s < 6; ++s)
            pk.p[6 * j + s] = (const float*)d_in[2 + 6 * j + s];

    const float* Wm  = (const float*)d_in[20];
    const float* gm  = (const float*)d_in[22];
    const float* bem = (const float*)d_in[23];
    const float* Wo  = (const float*)d_in[24];
    const float* bo  = (const float*)d_in[25];
    const float* go  = (const float*)d_in[26];
    const float* beo = (const float*)d_in[27];

    // ws layout: [0, 320K) u32 part[320][256]; [320K,321.25K) u32 hist[320];
    //            [321.5K..) f32 e_tab[480], spre0[480], spre1[480];
    //            [336K, 336K+256K) u32 pkbits[256][256]
    uint*  part   = (uint*)d_ws;
    uint*  hist   = (uint*)((char*)d_ws + 327680);
    float* e_tab  = (float*)((char*)d_ws + 329216);
    float* spre0  = (float*)((char*)d_ws + 331264);
    float* spre1  = (float*)((char*)d_ws + 333312);
    uint*  pkbits = (uint*)((char*)d_ws + 344064);

    k_prep<<<BATCH, 512, 0, stream>>>(x, perms, part, pkbits);
    k_hred<<<320, 64, 0, stream>>>(part, hist);
    k_etab3<<<480, 256, 0, stream>>>(pk, hist, e_tab);
    k_pre2<<<480, 256, 0, stream>>>(hist, e_tab, Wm, gm, bem, Wo, bo, spre0, spre1);
    k_wfin6<<<BATCH, 512, 0, stream>>>(pkbits, hist, spre0, spre1, go, beo,
                                       (float*)d_out);
}